// Round 1
// baseline (737.617 us; speedup 1.0000x reference)
//
#include <hip/hip_runtime.h>

#define T_LEN 1000
#define B_N 8
#define IN_CH 80
#define CONV_CH 256
#define CCEP_N 222
#define TT 8

__device__ __constant__ float STEP = 6.28318530717958647692f / 1024.f; // 2*pi/1024

// ---------------- conv1: (B,T,80) -> (B,T,256), k=3 same, relu ----------------
__global__ __launch_bounds__(256) void k_conv1(const float* __restrict__ x,
    const float* __restrict__ W, const float* __restrict__ bias,
    float* __restrict__ out) {
  const int b = blockIdx.y;
  const int t0 = blockIdx.x * TT;
  const int o = threadIdx.x;
  __shared__ float xs[TT + 2][IN_CH];
  for (int idx = threadIdx.x; idx < (TT + 2) * IN_CH; idx += 256) {
    int row = idx / IN_CH, col = idx - row * IN_CH;
    int t = t0 - 1 + row;
    xs[row][col] = (t >= 0 && t < T_LEN) ? x[(b * T_LEN + t) * IN_CH + col] : 0.f;
  }
  __syncthreads();
  float acc[TT];
  float bv = bias[o];
#pragma unroll
  for (int j = 0; j < TT; j++) acc[j] = bv;
  const float* wr = W + o * (IN_CH * 3);
  for (int i = 0; i < IN_CH; i++) {
    float w0 = wr[i * 3], w1 = wr[i * 3 + 1], w2 = wr[i * 3 + 2];
#pragma unroll
    for (int j = 0; j < TT; j++) {
      acc[j] = fmaf(xs[j][i], w0, acc[j]);
      acc[j] = fmaf(xs[j + 1][i], w1, acc[j]);
      acc[j] = fmaf(xs[j + 2][i], w2, acc[j]);
    }
  }
#pragma unroll
  for (int j = 0; j < TT; j++)
    out[(b * T_LEN + t0 + j) * CONV_CH + o] = fmaxf(acc[j], 0.f);
}

// ------------- grouped conv: (B,T,256)->(B,T,256), groups=8, relu -------------
__global__ __launch_bounds__(256) void k_convg(const float* __restrict__ h,
    const float* __restrict__ W, const float* __restrict__ bias,
    float* __restrict__ out) {
  const int b = blockIdx.y;
  const int t0 = blockIdx.x * TT;
  const int o = threadIdx.x;
  const int cb = (o >> 5) << 5;  // group base channel
  __shared__ float hs[TT + 2][CONV_CH];
  for (int idx = threadIdx.x; idx < (TT + 2) * CONV_CH; idx += 256) {
    int row = idx >> 8, col = idx & 255;
    int t = t0 - 1 + row;
    hs[row][col] = (t >= 0 && t < T_LEN) ? h[(b * T_LEN + t) * CONV_CH + col] : 0.f;
  }
  __syncthreads();
  float acc[TT];
  float bv = bias[o];
#pragma unroll
  for (int j = 0; j < TT; j++) acc[j] = bv;
  const float* wr = W + o * (32 * 3);
  for (int i = 0; i < 32; i++) {
    float w0 = wr[i * 3], w1 = wr[i * 3 + 1], w2 = wr[i * 3 + 2];
    int c = cb + i;
#pragma unroll
    for (int j = 0; j < TT; j++) {
      acc[j] = fmaf(hs[j][c], w0, acc[j]);
      acc[j] = fmaf(hs[j + 1][c], w1, acc[j]);
      acc[j] = fmaf(hs[j + 2][c], w2, acc[j]);
    }
  }
#pragma unroll
  for (int j = 0; j < TT; j++)
    out[(b * T_LEN + t0 + j) * CONV_CH + o] = fmaxf(acc[j], 0.f);
}

// -------- conv4: (B,T,256)->(B,T,222), k=3 same, + divide by quefrency --------
__global__ __launch_bounds__(256) void k_conv4(const float* __restrict__ h,
    const float* __restrict__ W, const float* __restrict__ bias,
    float* __restrict__ out) {
  const int b = blockIdx.y;
  const int t0 = blockIdx.x * TT;
  const int c = threadIdx.x;
  __shared__ float hs[TT + 2][CONV_CH];
  for (int idx = threadIdx.x; idx < (TT + 2) * CONV_CH; idx += 256) {
    int row = idx >> 8, col = idx & 255;
    int t = t0 - 1 + row;
    hs[row][col] = (t >= 0 && t < T_LEN) ? h[(b * T_LEN + t) * CONV_CH + col] : 0.f;
  }
  __syncthreads();
  if (c >= CCEP_N) return;
  float acc[TT];
  float bv = bias[c];
#pragma unroll
  for (int j = 0; j < TT; j++) acc[j] = bv;
  const float* wr = W + c * (CONV_CH * 3);
  for (int i = 0; i < CONV_CH; i++) {
    float w0 = wr[i * 3], w1 = wr[i * 3 + 1], w2 = wr[i * 3 + 2];
#pragma unroll
    for (int j = 0; j < TT; j++) {
      acc[j] = fmaf(hs[j][i], w0, acc[j]);
      acc[j] = fmaf(hs[j + 1][i], w1, acc[j]);
      acc[j] = fmaf(hs[j + 2][i], w2, acc[j]);
    }
  }
  // quef[c] = 111-c for c<111 else c-110
  float invq = 1.f / (float)((c < 111) ? (111 - c) : (c - 110));
#pragma unroll
  for (int j = 0; j < TT; j++)
    out[(b * T_LEN + t0 + j) * CCEP_N + c] = acc[j] * invq;
}

// ---- filter generation: cc (B*T,222) -> imp (B*T,1024) -----------------------
// Y[k] = sum_m cc[m] e^{-2pi i (m+401) k /1024}, k=0..512
// G[k] = 10^Yr * e^{i Yi};  imp[n] = (1/1024)(G0 + (-1)^n G512 + 2 sum_{k=1..511} Re(G_k e^{2pi i k n/1024}))
__global__ __launch_bounds__(256) void k_filtgen(const float* __restrict__ cc,
                                                 float* __restrict__ imp) {
  const int bt = blockIdx.x;
  const int tid = threadIdx.x;
  __shared__ float ccs[CCEP_N];
  __shared__ __align__(16) float Gs[1026];  // interleaved Gr,Gi for k=0..512
  if (tid < CCEP_N) ccs[tid] = cc[bt * CCEP_N + tid];
  __syncthreads();

  for (int k = tid; k <= 512; k += 256) {
    int r0 = (401 * k) & 1023;
    float er, ei, wr, wi;
    sincosf(STEP * (float)r0, &ei, &er);  // e^{i*2pi*r0/1024}
    sincosf(STEP * (float)k, &wi, &wr);   // rotation step e^{i*2pi*k/1024}
    float yr = 0.f, yi = 0.f;
    for (int m = 0; m < CCEP_N; m++) {
      float cv = ccs[m];
      yr = fmaf(cv, er, yr);
      yi = fmaf(-cv, ei, yi);
      float tt = fmaf(er, wr, -ei * wi);
      ei = fmaf(er, wi, ei * wr);
      er = tt;
    }
    float mag = exp10f(yr);
    float sy, cy;
    sincosf(yi, &sy, &cy);
    float gr = mag * cy, gi = mag * sy;
    if (k == 0) { gr *= 0.5f; gi *= 0.5f; }  // fold G0 once into doubled sum
    Gs[2 * k] = gr;
    Gs[2 * k + 1] = gi;
  }
  __syncthreads();

  // radix-4 over n: thread tid produces n, n+256, n+512, n+768
  const int n = tid;
  float er = 1.f, ei = 0.f, wr, wi;
  sincosf(STEP * (float)n, &wi, &wr);  // e^{i*2pi*n/1024}
  float cr0 = 0.f, cr1 = 0.f, cr2 = 0.f, cr3 = 0.f, ci1 = 0.f, ci3 = 0.f;
  for (int k = 0; k < 512; k += 4) {
    const float4 g01 = *reinterpret_cast<const float4*>(&Gs[2 * k]);
    const float4 g23 = *reinterpret_cast<const float4*>(&Gs[2 * k + 4]);
    // k+0 (j=0): only real part needed
    cr0 = fmaf(g01.x, er, cr0); cr0 = fmaf(-g01.y, ei, cr0);
    { float tt = fmaf(er, wr, -ei * wi); ei = fmaf(er, wi, ei * wr); er = tt; }
    // k+1 (j=1)
    cr1 = fmaf(g01.z, er, cr1); cr1 = fmaf(-g01.w, ei, cr1);
    ci1 = fmaf(g01.z, ei, ci1); ci1 = fmaf(g01.w, er, ci1);
    { float tt = fmaf(er, wr, -ei * wi); ei = fmaf(er, wi, ei * wr); er = tt; }
    // k+2 (j=2): only real part needed
    cr2 = fmaf(g23.x, er, cr2); cr2 = fmaf(-g23.y, ei, cr2);
    { float tt = fmaf(er, wr, -ei * wi); ei = fmaf(er, wi, ei * wr); er = tt; }
    // k+3 (j=3)
    cr3 = fmaf(g23.z, er, cr3); cr3 = fmaf(-g23.w, ei, cr3);
    ci3 = fmaf(g23.z, ei, ci3); ci3 = fmaf(g23.w, er, ci3);
    { float tt = fmaf(er, wr, -ei * wi); ei = fmaf(er, wi, ei * wr); er = tt; }
  }
  float g512 = Gs[1024];
  float s512h = 0.5f * ((n & 1) ? -g512 : g512);
  const float SC = 1.f / 512.f;
  float* op = imp + bt * 1024;
  op[n]       = SC * (cr0 + cr1 + cr2 + cr3 + s512h);
  op[n + 256] = SC * (cr0 - ci1 - cr2 + ci3 + s512h);
  op[n + 512] = SC * (cr0 - cr1 + cr2 - cr3 + s512h);
  op[n + 768] = SC * (cr0 + ci1 - cr2 - ci3 + s512h);
}

// ---- correlation + window: corr[n] = sum_k fr[k]*imp[k+511-n], n=0..511 ------
__global__ __launch_bounds__(256) void k_corr(const float* __restrict__ z,
    const float* __restrict__ imp, float* __restrict__ zw) {
  const int bt = blockIdx.x;
  const int b = bt / T_LEN, t = bt - b * T_LEN;
  const int tid = threadIdx.x;
  __shared__ float imps[1024];
  __shared__ float fr[512];
  const float* ip = imp + bt * 1024;
#pragma unroll
  for (int j = 0; j < 4; j++) imps[tid + 256 * j] = ip[tid + 256 * j];
  const float* zb = z + b * 256000;
#pragma unroll
  for (int j = 0; j < 2; j++) {
    int k = tid + 256 * j;
    int zi = t * 256 + k - 255;
    fr[k] = (zi >= 0 && zi < 256000) ? zb[zi] : 0.f;
  }
  __syncthreads();
  const float* p1 = &imps[511 - tid];  // n1 = tid
  const float* p2 = &imps[255 - tid];  // n2 = tid+256
  float a1 = 0.f, a2 = 0.f;
#pragma unroll 8
  for (int k = 0; k < 512; ++k) {
    float f = fr[k];
    a1 = fmaf(f, p1[k], a1);
    a2 = fmaf(f, p2[k], a2);
  }
  // win[n] = 0.5*(1 - cos(2*pi*n/512))
  float w1 = 0.5f - 0.5f * cosf(STEP * 2.f * (float)tid);
  float w2 = 0.5f - 0.5f * cosf(STEP * 2.f * (float)(tid + 256));
  zw[bt * 512 + tid] = a1 * w1;
  zw[bt * 512 + tid + 256] = a2 * w2;
}

// ---- overlap-add: out[b, t*256+j] = zw[b,t,j] + zw[b,(t-1)%T, 256+j] ---------
__global__ __launch_bounds__(256) void k_ola(const float* __restrict__ zw,
                                             float* __restrict__ out) {
  int idx = blockIdx.x * 256 + threadIdx.x;  // 0 .. 2,048,000
  int j = idx & 255;
  int bt = idx >> 8;                 // b*1000 + t
  int t = bt % T_LEN;
  int btm = (t == 0) ? bt + (T_LEN - 1) : bt - 1;
  out[idx] = zw[bt * 512 + j] + zw[btm * 512 + 256 + j];
}

extern "C" void kernel_launch(void* const* d_in, const int* in_sizes, int n_in,
                              void* d_out, int out_size, void* d_ws, size_t ws_size,
                              hipStream_t stream) {
  const float* x  = (const float*)d_in[0];
  const float* z  = (const float*)d_in[1];
  const float* W1 = (const float*)d_in[2];
  const float* b1 = (const float*)d_in[3];
  const float* W2 = (const float*)d_in[4];
  const float* b2 = (const float*)d_in[5];
  const float* W3 = (const float*)d_in[6];
  const float* b3 = (const float*)d_in[7];
  const float* W4 = (const float*)d_in[8];
  const float* b4 = (const float*)d_in[9];

  float* ws   = (float*)d_ws;
  float* bufA = ws;                   // 2,048,000 f32 (h1 / h3)
  float* bufB = ws + 2048000;         // 2,048,000 f32 (h2 / cc)
  float* impB = ws + 4096000;         // 8,192,000 f32
  float* zwB  = ws + 12288000;        // 4,096,000 f32
  // total 16,384,000 f32 = 65.5 MB

  dim3 blk(256);
  dim3 cgrid(T_LEN / TT, B_N);  // (125, 8)
  k_conv1<<<cgrid, blk, 0, stream>>>(x, W1, b1, bufA);
  k_convg<<<cgrid, blk, 0, stream>>>(bufA, W2, b2, bufB);
  k_convg<<<cgrid, blk, 0, stream>>>(bufB, W3, b3, bufA);
  k_conv4<<<cgrid, blk, 0, stream>>>(bufA, W4, b4, bufB);
  k_filtgen<<<B_N * T_LEN, blk, 0, stream>>>(bufB, impB);
  k_corr<<<B_N * T_LEN, blk, 0, stream>>>(z, impB, zwB);
  k_ola<<<B_N * T_LEN, blk, 0, stream>>>(zwB, (float*)d_out);
}

// Round 2
// 359.117 us; speedup vs baseline: 2.0540x; 2.0540x over previous
//
#include <hip/hip_runtime.h>

#define T_LEN 1000
#define B_N 8
#define IN_CH 80
#define CONV_CH 256
#define CCEP_N 222
#define TT 8

__device__ __constant__ float STEP = 6.28318530717958647692f / 1024.f; // 2*pi/1024

// ---------------- conv1: (B,T,80) -> (B,T,256), k=3 same, relu ----------------
__global__ __launch_bounds__(256) void k_conv1(const float* __restrict__ x,
    const float* __restrict__ W, const float* __restrict__ bias,
    float* __restrict__ out) {
  const int b = blockIdx.y;
  const int t0 = blockIdx.x * TT;
  const int o = threadIdx.x;
  __shared__ float xs[TT + 2][IN_CH];
  for (int idx = threadIdx.x; idx < (TT + 2) * IN_CH; idx += 256) {
    int row = idx / IN_CH, col = idx - row * IN_CH;
    int t = t0 - 1 + row;
    xs[row][col] = (t >= 0 && t < T_LEN) ? x[(b * T_LEN + t) * IN_CH + col] : 0.f;
  }
  __syncthreads();
  float acc[TT];
  float bv = bias[o];
#pragma unroll
  for (int j = 0; j < TT; j++) acc[j] = bv;
  const float* wr = W + o * (IN_CH * 3);
  for (int i = 0; i < IN_CH; i++) {
    float w0 = wr[i * 3], w1 = wr[i * 3 + 1], w2 = wr[i * 3 + 2];
#pragma unroll
    for (int j = 0; j < TT; j++) {
      acc[j] = fmaf(xs[j][i], w0, acc[j]);
      acc[j] = fmaf(xs[j + 1][i], w1, acc[j]);
      acc[j] = fmaf(xs[j + 2][i], w2, acc[j]);
    }
  }
#pragma unroll
  for (int j = 0; j < TT; j++)
    out[(b * T_LEN + t0 + j) * CONV_CH + o] = fmaxf(acc[j], 0.f);
}

// ------------- grouped conv: (B,T,256)->(B,T,256), groups=8, relu -------------
__global__ __launch_bounds__(256) void k_convg(const float* __restrict__ h,
    const float* __restrict__ W, const float* __restrict__ bias,
    float* __restrict__ out) {
  const int b = blockIdx.y;
  const int t0 = blockIdx.x * TT;
  const int o = threadIdx.x;
  const int cb = (o >> 5) << 5;  // group base channel
  __shared__ float hs[TT + 2][CONV_CH];
  for (int idx = threadIdx.x; idx < (TT + 2) * CONV_CH; idx += 256) {
    int row = idx >> 8, col = idx & 255;
    int t = t0 - 1 + row;
    hs[row][col] = (t >= 0 && t < T_LEN) ? h[(b * T_LEN + t) * CONV_CH + col] : 0.f;
  }
  __syncthreads();
  float acc[TT];
  float bv = bias[o];
#pragma unroll
  for (int j = 0; j < TT; j++) acc[j] = bv;
  const float* wr = W + o * (32 * 3);
  for (int i = 0; i < 32; i++) {
    float w0 = wr[i * 3], w1 = wr[i * 3 + 1], w2 = wr[i * 3 + 2];
    int c = cb + i;
#pragma unroll
    for (int j = 0; j < TT; j++) {
      acc[j] = fmaf(hs[j][c], w0, acc[j]);
      acc[j] = fmaf(hs[j + 1][c], w1, acc[j]);
      acc[j] = fmaf(hs[j + 2][c], w2, acc[j]);
    }
  }
#pragma unroll
  for (int j = 0; j < TT; j++)
    out[(b * T_LEN + t0 + j) * CONV_CH + o] = fmaxf(acc[j], 0.f);
}

// -------- conv4: (B,T,256)->(B,T,222), k=3 same, + divide by quefrency --------
__global__ __launch_bounds__(256) void k_conv4(const float* __restrict__ h,
    const float* __restrict__ W, const float* __restrict__ bias,
    float* __restrict__ out) {
  const int b = blockIdx.y;
  const int t0 = blockIdx.x * TT;
  const int c = threadIdx.x;
  __shared__ float hs[TT + 2][CONV_CH];
  for (int idx = threadIdx.x; idx < (TT + 2) * CONV_CH; idx += 256) {
    int row = idx >> 8, col = idx & 255;
    int t = t0 - 1 + row;
    hs[row][col] = (t >= 0 && t < T_LEN) ? h[(b * T_LEN + t) * CONV_CH + col] : 0.f;
  }
  __syncthreads();
  if (c >= CCEP_N) return;
  float acc[TT];
  float bv = bias[c];
#pragma unroll
  for (int j = 0; j < TT; j++) acc[j] = bv;
  const float* wr = W + c * (CONV_CH * 3);
  for (int i = 0; i < CONV_CH; i++) {
    float w0 = wr[i * 3], w1 = wr[i * 3 + 1], w2 = wr[i * 3 + 2];
#pragma unroll
    for (int j = 0; j < TT; j++) {
      acc[j] = fmaf(hs[j][i], w0, acc[j]);
      acc[j] = fmaf(hs[j + 1][i], w1, acc[j]);
      acc[j] = fmaf(hs[j + 2][i], w2, acc[j]);
    }
  }
  float invq = 1.f / (float)((c < 111) ? (111 - c) : (c - 110));
#pragma unroll
  for (int j = 0; j < TT; j++)
    out[(b * T_LEN + t0 + j) * CCEP_N + c] = acc[j] * invq;
}

// ============================ fused FFT kernel ================================
// Per (b,t):  Y = FFT1024(c_pad);  G = 10^Yr * e^{i Yi}  (elementwise, so order
// agnostic);  Fz = FFT1024(fr_pad);  S = conj(Fz)*G;  C = IFFT1024(S) (real);
// zw[n] = C[511-n] * win[n].   imp is never materialized: FFT(imp) == G and the
// 512-tap correlation has no circular wrap at N=1024 (indices span [0,1022]).
// In-place DIF forward (natural->digitrev) + DIT inverse (digitrev->natural):
// pointwise ops run in scrambled order; no bit reversal needed.

__device__ __forceinline__ float2 cmul(float2 a, float2 b) {
  return make_float2(fmaf(a.x, b.x, -(a.y * b.y)), fmaf(a.x, b.y, a.y * b.x));
}
__device__ __forceinline__ float2 cadd(float2 a, float2 b) { return make_float2(a.x + b.x, a.y + b.y); }
__device__ __forceinline__ float2 csub(float2 a, float2 b) { return make_float2(a.x - b.x, a.y - b.y); }

#define LIDX(i) ((i) + ((i) >> 2))   // skew to break power-of-2 bank strides

template <int M>
__device__ __forceinline__ void fwd_stage(float2* __restrict__ A, float2* __restrict__ B, int j) {
  constexpr int Q = M >> 2;
  const int pos = j & (Q - 1);
  const int base = ((j - pos) << 2) + pos;   // (j/Q)*M + pos
  float s, c;
  __sincosf((6.28318530717958647692f / M) * (float)pos, &s, &c);
  const float2 w1 = make_float2(c, -s);
  const float2 w2 = cmul(w1, w1);
  const float2 w3 = cmul(w2, w1);
#pragma unroll
  for (int arr = 0; arr < 2; ++arr) {
    float2* X = arr ? B : A;
    float2 a = X[LIDX(base)], b = X[LIDX(base + Q)];
    float2 cc = X[LIDX(base + 2 * Q)], d = X[LIDX(base + 3 * Q)];
    float2 t0 = cadd(a, cc), t1 = csub(a, cc), t2 = cadd(b, d), bd = csub(b, d);
    float2 t3 = make_float2(bd.y, -bd.x);            // -i*(b-d)
    X[LIDX(base)]         = cadd(t0, t2);
    X[LIDX(base + Q)]     = cmul(cadd(t1, t3), w1);
    X[LIDX(base + 2 * Q)] = cmul(csub(t0, t2), w2);
    X[LIDX(base + 3 * Q)] = cmul(csub(t1, t3), w3);
  }
}

template <int M>
__device__ __forceinline__ void inv_stage(float2* __restrict__ X, int j) {
  constexpr int Q = M >> 2;
  const int pos = j & (Q - 1);
  const int base = ((j - pos) << 2) + pos;
  float s, c;
  __sincosf((6.28318530717958647692f / M) * (float)pos, &s, &c);
  const float2 w1 = make_float2(c, s);               // conj twiddles
  const float2 w2 = cmul(w1, w1);
  const float2 w3 = cmul(w2, w1);
  float2 a = X[LIDX(base)];
  float2 b = cmul(X[LIDX(base + Q)], w1);
  float2 cc = cmul(X[LIDX(base + 2 * Q)], w2);
  float2 d = cmul(X[LIDX(base + 3 * Q)], w3);
  float2 t0 = cadd(a, cc), t1 = csub(a, cc), t2 = cadd(b, d), bd = csub(b, d);
  float2 t3 = make_float2(-bd.y, bd.x);              // +i*(b-d)
  X[LIDX(base)]         = cadd(t0, t2);
  X[LIDX(base + Q)]     = cadd(t1, t3);
  X[LIDX(base + 2 * Q)] = csub(t0, t2);
  X[LIDX(base + 3 * Q)] = csub(t1, t3);
}

__global__ __launch_bounds__(256) void k_fft(const float* __restrict__ cc,
    const float* __restrict__ z, float* __restrict__ zw) {
  const int bt = blockIdx.x;
  const int b = bt / T_LEN, t = bt - b * T_LEN;
  const int j = threadIdx.x;
  __shared__ float2 U[1280];   // cepstrum -> Y -> G
  __shared__ float2 V[1280];   // frame    -> Fz -> S -> corr

  // load: U = c_pad (cc at [401,623)), V = fr_pad (512 frame samples)
  const float* zb = z + b * 256000;
#pragma unroll
  for (int r = 0; r < 4; ++r) {
    int p = j + 256 * r;
    float uv = 0.f;
    if (p >= 401 && p < 401 + CCEP_N) uv = cc[bt * CCEP_N + (p - 401)];
    U[LIDX(p)] = make_float2(uv, 0.f);
    float fv = 0.f;
    if (p < 512) {
      int zi = t * 256 + p - 255;
      if (zi >= 0 && zi < 256000) fv = zb[zi];
    }
    V[LIDX(p)] = make_float2(fv, 0.f);
  }
  __syncthreads();

  fwd_stage<1024>(U, V, j); __syncthreads();
  fwd_stage<256>(U, V, j);  __syncthreads();
  fwd_stage<64>(U, V, j);   __syncthreads();
  fwd_stage<16>(U, V, j);   __syncthreads();

  // fused: fwd stage M=4 (twiddles=1) + pointwise + inv stage M=4 (twiddles=1)
  {
    const int base = 4 * j;
    float2 u[4], v[4];
#pragma unroll
    for (int q = 0; q < 4; ++q) { u[q] = U[LIDX(base + q)]; v[q] = V[LIDX(base + q)]; }
    // forward radix-4 butterflies (no twiddles at M=4)
    float2 Yq[4], Fq[4];
    {
      float2 t0 = cadd(u[0], u[2]), t1 = csub(u[0], u[2]), t2 = cadd(u[1], u[3]), bd = csub(u[1], u[3]);
      float2 t3 = make_float2(bd.y, -bd.x);
      Yq[0] = cadd(t0, t2); Yq[1] = cadd(t1, t3); Yq[2] = csub(t0, t2); Yq[3] = csub(t1, t3);
    }
    {
      float2 t0 = cadd(v[0], v[2]), t1 = csub(v[0], v[2]), t2 = cadd(v[1], v[3]), bd = csub(v[1], v[3]);
      float2 t3 = make_float2(bd.y, -bd.x);
      Fq[0] = cadd(t0, t2); Fq[1] = cadd(t1, t3); Fq[2] = csub(t0, t2); Fq[3] = csub(t1, t3);
    }
    // pointwise: G = 10^Yr * e^{i Yi};  S = conj(Fz) * G
    float2 S[4];
#pragma unroll
    for (int q = 0; q < 4; ++q) {
      float mag = exp10f(Yq[q].x);
      float sy, cy;
      sincosf(Yq[q].y, &sy, &cy);
      float gr = mag * cy, gi = mag * sy;
      S[q] = make_float2(fmaf(Fq[q].x, gr, Fq[q].y * gi),
                         fmaf(Fq[q].x, gi, -(Fq[q].y * gr)));
    }
    // inverse radix-4 butterfly (no twiddles at M=4)
    {
      float2 t0 = cadd(S[0], S[2]), t1 = csub(S[0], S[2]), t2 = cadd(S[1], S[3]), bd = csub(S[1], S[3]);
      float2 t3 = make_float2(-bd.y, bd.x);
      V[LIDX(base)]     = cadd(t0, t2);
      V[LIDX(base + 1)] = cadd(t1, t3);
      V[LIDX(base + 2)] = csub(t0, t2);
      V[LIDX(base + 3)] = csub(t1, t3);
    }
  }
  __syncthreads();

  inv_stage<16>(V, j);   __syncthreads();
  inv_stage<64>(V, j);   __syncthreads();
  inv_stage<256>(V, j);  __syncthreads();
  inv_stage<1024>(V, j); __syncthreads();

  // zw[n] = corr[n]*win[n],  corr[n] = C[511-n]/1024
  const float ISC = 1.0f / 1024.0f;
  {
    int n = j;                                    // n in [0,256)
    float cv = V[LIDX(511 - n)].x * ISC;
    float w = 0.5f - 0.5f * __cosf(STEP * 2.f * (float)n);
    zw[bt * 512 + n] = cv * w;
    n = j + 256;                                  // n in [256,512)
    cv = V[LIDX(511 - n)].x * ISC;
    w = 0.5f - 0.5f * __cosf(STEP * 2.f * (float)n);
    zw[bt * 512 + n] = cv * w;
  }
}

// ---- overlap-add: out[b, t*256+j] = zw[b,t,j] + zw[b,(t-1)%T, 256+j] ---------
__global__ __launch_bounds__(256) void k_ola(const float* __restrict__ zw,
                                             float* __restrict__ out) {
  int idx = blockIdx.x * 256 + threadIdx.x;
  int j = idx & 255;
  int bt = idx >> 8;
  int t = bt % T_LEN;
  int btm = (t == 0) ? bt + (T_LEN - 1) : bt - 1;
  out[idx] = zw[bt * 512 + j] + zw[btm * 512 + 256 + j];
}

extern "C" void kernel_launch(void* const* d_in, const int* in_sizes, int n_in,
                              void* d_out, int out_size, void* d_ws, size_t ws_size,
                              hipStream_t stream) {
  const float* x  = (const float*)d_in[0];
  const float* z  = (const float*)d_in[1];
  const float* W1 = (const float*)d_in[2];
  const float* b1 = (const float*)d_in[3];
  const float* W2 = (const float*)d_in[4];
  const float* b2 = (const float*)d_in[5];
  const float* W3 = (const float*)d_in[6];
  const float* b3 = (const float*)d_in[7];
  const float* W4 = (const float*)d_in[8];
  const float* b4 = (const float*)d_in[9];

  float* ws   = (float*)d_ws;
  float* bufA = ws;                   // 2,048,000 f32
  float* bufB = ws + 2048000;         // 2,048,000 f32
  float* zwB  = ws + 4096000;         // 4,096,000 f32

  dim3 blk(256);
  dim3 cgrid(T_LEN / TT, B_N);  // (125, 8)
  k_conv1<<<cgrid, blk, 0, stream>>>(x, W1, b1, bufA);
  k_convg<<<cgrid, blk, 0, stream>>>(bufA, W2, b2, bufB);
  k_convg<<<cgrid, blk, 0, stream>>>(bufB, W3, b3, bufA);
  k_conv4<<<cgrid, blk, 0, stream>>>(bufA, W4, b4, bufB);
  k_fft<<<B_N * T_LEN, blk, 0, stream>>>(bufB, z, zwB);
  k_ola<<<B_N * T_LEN, blk, 0, stream>>>(zwB, (float*)d_out);
}

// Round 3
// 263.629 us; speedup vs baseline: 2.7979x; 1.3622x over previous
//
#include <hip/hip_runtime.h>

#define T_LEN 1000
#define B_N 8
#define IN_CH 80
#define CONV_CH 256
#define CCEP_N 222

__device__ __constant__ float STEP = 6.28318530717958647692f / 1024.f; // 2*pi/1024

// ===================== weight transpose kernels (run every call) ==============
// W1 (256,80,3) -> Wt1[k240][o256]
__global__ __launch_bounds__(256) void k_tw1(const float* __restrict__ W,
                                             float* __restrict__ Wt) {
  int e = blockIdx.x * 256 + threadIdx.x;   // 61440
  int o = e / 240, k = e - o * 240;
  Wt[k * 256 + o] = W[e];
}
// W2/W3 (256,32,3) -> Wt[k96][o256]
__global__ __launch_bounds__(256) void k_tw2(const float* __restrict__ W,
                                             float* __restrict__ Wt) {
  int e = blockIdx.x * 256 + threadIdx.x;   // 24576
  int o = e / 96, k = e - o * 96;
  Wt[k * 256 + o] = W[e];
}
// W4 (222,256,3) -> Wt4[k768][c224], scaled by 1/quef[c]
__global__ __launch_bounds__(256) void k_tw4(const float* __restrict__ W,
                                             float* __restrict__ Wt) {
  int e = blockIdx.x * 256 + threadIdx.x;   // 170496 = 222*768
  int c = e / 768, k = e - c * 768;
  float invq = 1.f / (float)((c < 111) ? (111 - c) : (c - 110));
  Wt[k * 224 + c] = W[e] * invq;
}

// ---------------- conv1: (B,T,80) -> (B,T,256), k=3 same, relu ----------------
// TT=10. hs transposed [80][12]; weight reads coalesced from Wt1.
__global__ __launch_bounds__(256) void k_conv1t(const float* __restrict__ x,
    const float* __restrict__ Wt, const float* __restrict__ bias,
    float* __restrict__ out) {
  const int b = blockIdx.y;
  const int t0 = blockIdx.x * 10;
  const int o = threadIdx.x;
  __shared__ float hs[IN_CH * 12];
  for (int e = threadIdx.x; e < 12 * IN_CH; e += 256) {
    int r = e / IN_CH, c = e - r * IN_CH;
    int t = t0 - 1 + r;
    hs[c * 12 + r] = (t >= 0 && t < T_LEN) ? x[(b * T_LEN + t) * IN_CH + c] : 0.f;
  }
  __syncthreads();
  float acc[10];
  float bv = bias[o];
#pragma unroll
  for (int j = 0; j < 10; j++) acc[j] = bv;
  for (int i = 0; i < IN_CH; i++) {
    float w0 = Wt[(3 * i + 0) * 256 + o];
    float w1 = Wt[(3 * i + 1) * 256 + o];
    float w2 = Wt[(3 * i + 2) * 256 + o];
    const float* row = &hs[i * 12];
    float a[12];
    *(float4*)&a[0] = *(const float4*)(row + 0);
    *(float4*)&a[4] = *(const float4*)(row + 4);
    *(float4*)&a[8] = *(const float4*)(row + 8);
#pragma unroll
    for (int j = 0; j < 10; j++) {
      acc[j] = fmaf(a[j], w0, acc[j]);
      acc[j] = fmaf(a[j + 1], w1, acc[j]);
      acc[j] = fmaf(a[j + 2], w2, acc[j]);
    }
  }
#pragma unroll
  for (int j = 0; j < 10; j++)
    out[(b * T_LEN + t0 + j) * CONV_CH + o] = fmaxf(acc[j], 0.f);
}

// ------------- grouped conv: (B,T,256)->(B,T,256), groups=8, relu -------------
__global__ __launch_bounds__(256) void k_convgt(const float* __restrict__ h,
    const float* __restrict__ Wt, const float* __restrict__ bias,
    float* __restrict__ out) {
  const int b = blockIdx.y;
  const int t0 = blockIdx.x * 10;
  const int o = threadIdx.x;
  const int cb = (o >> 5) << 5;
  __shared__ float hs[CONV_CH * 12];
  for (int e = threadIdx.x; e < 12 * CONV_CH; e += 256) {
    int r = e >> 8, c = e & 255;
    int t = t0 - 1 + r;
    hs[c * 12 + r] = (t >= 0 && t < T_LEN) ? h[(b * T_LEN + t) * CONV_CH + c] : 0.f;
  }
  __syncthreads();
  float acc[10];
  float bv = bias[o];
#pragma unroll
  for (int j = 0; j < 10; j++) acc[j] = bv;
  for (int i = 0; i < 32; i++) {
    float w0 = Wt[(3 * i + 0) * 256 + o];
    float w1 = Wt[(3 * i + 1) * 256 + o];
    float w2 = Wt[(3 * i + 2) * 256 + o];
    const float* row = &hs[(cb + i) * 12];
    float a[12];
    *(float4*)&a[0] = *(const float4*)(row + 0);
    *(float4*)&a[4] = *(const float4*)(row + 4);
    *(float4*)&a[8] = *(const float4*)(row + 8);
#pragma unroll
    for (int j = 0; j < 10; j++) {
      acc[j] = fmaf(a[j], w0, acc[j]);
      acc[j] = fmaf(a[j + 1], w1, acc[j]);
      acc[j] = fmaf(a[j + 2], w2, acc[j]);
    }
  }
#pragma unroll
  for (int j = 0; j < 10; j++)
    out[(b * T_LEN + t0 + j) * CONV_CH + o] = fmaxf(acc[j], 0.f);
}

// -------- conv4: (B,T,256)->(B,T,222), quef folded into Wt4/bias --------------
// TT=20. hs transposed [256][24 pitch]; coalesced weight reads from Wt4[768][224].
__global__ __launch_bounds__(256) void k_conv4t(const float* __restrict__ h,
    const float* __restrict__ Wt, const float* __restrict__ bias,
    float* __restrict__ out) {
  const int b = blockIdx.y;
  const int t0 = blockIdx.x * 20;
  const int c = threadIdx.x;
  __shared__ float hs[CONV_CH * 24];
  for (int e = threadIdx.x; e < 22 * CONV_CH; e += 256) {
    int r = e >> 8, ci = e & 255;
    int t = t0 - 1 + r;
    hs[ci * 24 + r] = (t >= 0 && t < T_LEN) ? h[(b * T_LEN + t) * CONV_CH + ci] : 0.f;
  }
  __syncthreads();
  if (c >= CCEP_N) return;
  float invq = 1.f / (float)((c < 111) ? (111 - c) : (c - 110));
  float acc[20];
  float bv = bias[c] * invq;
#pragma unroll
  for (int j = 0; j < 20; j++) acc[j] = bv;
  for (int i = 0; i < CONV_CH; i++) {
    float w0 = Wt[(3 * i + 0) * 224 + c];
    float w1 = Wt[(3 * i + 1) * 224 + c];
    float w2 = Wt[(3 * i + 2) * 224 + c];
    const float* row = &hs[i * 24];
    float a[22];
    *(float4*)&a[0]  = *(const float4*)(row + 0);
    *(float4*)&a[4]  = *(const float4*)(row + 4);
    *(float4*)&a[8]  = *(const float4*)(row + 8);
    *(float4*)&a[12] = *(const float4*)(row + 12);
    *(float4*)&a[16] = *(const float4*)(row + 16);
    *(float2*)&a[20] = *(const float2*)(row + 20);
#pragma unroll
    for (int j = 0; j < 20; j++) {
      acc[j] = fmaf(a[j], w0, acc[j]);
      acc[j] = fmaf(a[j + 1], w1, acc[j]);
      acc[j] = fmaf(a[j + 2], w2, acc[j]);
    }
  }
#pragma unroll
  for (int j = 0; j < 20; j++)
    out[(b * T_LEN + t0 + j) * CCEP_N + c] = acc[j];
}

// ============================ fused FFT kernel ================================
__device__ __forceinline__ float2 cmul(float2 a, float2 b) {
  return make_float2(fmaf(a.x, b.x, -(a.y * b.y)), fmaf(a.x, b.y, a.y * b.x));
}
__device__ __forceinline__ float2 cadd(float2 a, float2 b) { return make_float2(a.x + b.x, a.y + b.y); }
__device__ __forceinline__ float2 csub(float2 a, float2 b) { return make_float2(a.x - b.x, a.y - b.y); }

#define LIDX(i) ((i) + ((i) >> 2))

template <int M>
__device__ __forceinline__ void fwd_stage(float2* __restrict__ A, float2* __restrict__ B, int j) {
  constexpr int Q = M >> 2;
  const int pos = j & (Q - 1);
  const int base = ((j - pos) << 2) + pos;
  float s, c;
  __sincosf((6.28318530717958647692f / M) * (float)pos, &s, &c);
  const float2 w1 = make_float2(c, -s);
  const float2 w2 = cmul(w1, w1);
  const float2 w3 = cmul(w2, w1);
#pragma unroll
  for (int arr = 0; arr < 2; ++arr) {
    float2* X = arr ? B : A;
    float2 a = X[LIDX(base)], b = X[LIDX(base + Q)];
    float2 cc = X[LIDX(base + 2 * Q)], d = X[LIDX(base + 3 * Q)];
    float2 t0 = cadd(a, cc), t1 = csub(a, cc), t2 = cadd(b, d), bd = csub(b, d);
    float2 t3 = make_float2(bd.y, -bd.x);
    X[LIDX(base)]         = cadd(t0, t2);
    X[LIDX(base + Q)]     = cmul(cadd(t1, t3), w1);
    X[LIDX(base + 2 * Q)] = cmul(csub(t0, t2), w2);
    X[LIDX(base + 3 * Q)] = cmul(csub(t1, t3), w3);
  }
}

template <int M>
__device__ __forceinline__ void inv_stage(float2* __restrict__ X, int j) {
  constexpr int Q = M >> 2;
  const int pos = j & (Q - 1);
  const int base = ((j - pos) << 2) + pos;
  float s, c;
  __sincosf((6.28318530717958647692f / M) * (float)pos, &s, &c);
  const float2 w1 = make_float2(c, s);
  const float2 w2 = cmul(w1, w1);
  const float2 w3 = cmul(w2, w1);
  float2 a = X[LIDX(base)];
  float2 b = cmul(X[LIDX(base + Q)], w1);
  float2 cc = cmul(X[LIDX(base + 2 * Q)], w2);
  float2 d = cmul(X[LIDX(base + 3 * Q)], w3);
  float2 t0 = cadd(a, cc), t1 = csub(a, cc), t2 = cadd(b, d), bd = csub(b, d);
  float2 t3 = make_float2(-bd.y, bd.x);
  X[LIDX(base)]         = cadd(t0, t2);
  X[LIDX(base + Q)]     = cadd(t1, t3);
  X[LIDX(base + 2 * Q)] = csub(t0, t2);
  X[LIDX(base + 3 * Q)] = csub(t1, t3);
}

__global__ __launch_bounds__(256) void k_fft(const float* __restrict__ cc,
    const float* __restrict__ z, float* __restrict__ zw) {
  const int bt = blockIdx.x;
  const int b = bt / T_LEN, t = bt - b * T_LEN;
  const int j = threadIdx.x;
  __shared__ float2 U[1280];
  __shared__ float2 V[1280];

  const float* zb = z + b * 256000;
#pragma unroll
  for (int r = 0; r < 4; ++r) {
    int p = j + 256 * r;
    float uv = 0.f;
    if (p >= 401 && p < 401 + CCEP_N) uv = cc[bt * CCEP_N + (p - 401)];
    U[LIDX(p)] = make_float2(uv, 0.f);
    float fv = 0.f;
    if (p < 512) {
      int zi = t * 256 + p - 255;
      if (zi >= 0 && zi < 256000) fv = zb[zi];
    }
    V[LIDX(p)] = make_float2(fv, 0.f);
  }
  __syncthreads();

  fwd_stage<1024>(U, V, j); __syncthreads();
  fwd_stage<256>(U, V, j);  __syncthreads();
  fwd_stage<64>(U, V, j);   __syncthreads();
  fwd_stage<16>(U, V, j);   __syncthreads();

  {
    const int base = 4 * j;
    float2 u[4], v[4];
#pragma unroll
    for (int q = 0; q < 4; ++q) { u[q] = U[LIDX(base + q)]; v[q] = V[LIDX(base + q)]; }
    float2 Yq[4], Fq[4];
    {
      float2 t0 = cadd(u[0], u[2]), t1 = csub(u[0], u[2]), t2 = cadd(u[1], u[3]), bd = csub(u[1], u[3]);
      float2 t3 = make_float2(bd.y, -bd.x);
      Yq[0] = cadd(t0, t2); Yq[1] = cadd(t1, t3); Yq[2] = csub(t0, t2); Yq[3] = csub(t1, t3);
    }
    {
      float2 t0 = cadd(v[0], v[2]), t1 = csub(v[0], v[2]), t2 = cadd(v[1], v[3]), bd = csub(v[1], v[3]);
      float2 t3 = make_float2(bd.y, -bd.x);
      Fq[0] = cadd(t0, t2); Fq[1] = cadd(t1, t3); Fq[2] = csub(t0, t2); Fq[3] = csub(t1, t3);
    }
    float2 S[4];
#pragma unroll
    for (int q = 0; q < 4; ++q) {
      float mag = __expf(Yq[q].x * 2.30258509299404568402f);  // 10^x
      float sy, cy;
      __sincosf(Yq[q].y, &sy, &cy);
      float gr = mag * cy, gi = mag * sy;
      S[q] = make_float2(fmaf(Fq[q].x, gr, Fq[q].y * gi),
                         fmaf(Fq[q].x, gi, -(Fq[q].y * gr)));
    }
    {
      float2 t0 = cadd(S[0], S[2]), t1 = csub(S[0], S[2]), t2 = cadd(S[1], S[3]), bd = csub(S[1], S[3]);
      float2 t3 = make_float2(-bd.y, bd.x);
      V[LIDX(base)]     = cadd(t0, t2);
      V[LIDX(base + 1)] = cadd(t1, t3);
      V[LIDX(base + 2)] = csub(t0, t2);
      V[LIDX(base + 3)] = csub(t1, t3);
    }
  }
  __syncthreads();

  inv_stage<16>(V, j);   __syncthreads();
  inv_stage<64>(V, j);   __syncthreads();
  inv_stage<256>(V, j);  __syncthreads();
  inv_stage<1024>(V, j); __syncthreads();

  const float ISC = 1.0f / 1024.0f;
  {
    int n = j;
    float cv = V[LIDX(511 - n)].x * ISC;
    float w = 0.5f - 0.5f * __cosf(STEP * 2.f * (float)n);
    zw[bt * 512 + n] = cv * w;
    n = j + 256;
    cv = V[LIDX(511 - n)].x * ISC;
    w = 0.5f - 0.5f * __cosf(STEP * 2.f * (float)n);
    zw[bt * 512 + n] = cv * w;
  }
}

// ---- overlap-add --------------------------------------------------------------
__global__ __launch_bounds__(256) void k_ola(const float* __restrict__ zw,
                                             float* __restrict__ out) {
  int idx = blockIdx.x * 256 + threadIdx.x;
  int j = idx & 255;
  int bt = idx >> 8;
  int t = bt % T_LEN;
  int btm = (t == 0) ? bt + (T_LEN - 1) : bt - 1;
  out[idx] = zw[bt * 512 + j] + zw[btm * 512 + 256 + j];
}

extern "C" void kernel_launch(void* const* d_in, const int* in_sizes, int n_in,
                              void* d_out, int out_size, void* d_ws, size_t ws_size,
                              hipStream_t stream) {
  const float* x  = (const float*)d_in[0];
  const float* z  = (const float*)d_in[1];
  const float* W1 = (const float*)d_in[2];
  const float* b1 = (const float*)d_in[3];
  const float* W2 = (const float*)d_in[4];
  const float* b2 = (const float*)d_in[5];
  const float* W3 = (const float*)d_in[6];
  const float* b3 = (const float*)d_in[7];
  const float* W4 = (const float*)d_in[8];
  const float* b4 = (const float*)d_in[9];

  float* ws   = (float*)d_ws;
  float* bufA = ws;                   // 2,048,000
  float* bufB = ws + 2048000;         // 2,048,000
  float* zwB  = ws + 4096000;         // 4,096,000
  float* Wt1  = ws + 8192000;         //    61,440
  float* Wt2  = ws + 8253440;         //    24,576
  float* Wt3  = ws + 8278016;         //    24,576
  float* Wt4  = ws + 8302592;         //   172,032

  dim3 blk(256);
  k_tw1<<<240, blk, 0, stream>>>(W1, Wt1);
  k_tw2<<<96,  blk, 0, stream>>>(W2, Wt2);
  k_tw2<<<96,  blk, 0, stream>>>(W3, Wt3);
  k_tw4<<<666, blk, 0, stream>>>(W4, Wt4);

  dim3 cgrid10(T_LEN / 10, B_N);  // (100, 8)
  dim3 cgrid20(T_LEN / 20, B_N);  // (50, 8)
  k_conv1t<<<cgrid10, blk, 0, stream>>>(x, Wt1, b1, bufA);
  k_convgt<<<cgrid10, blk, 0, stream>>>(bufA, Wt2, b2, bufB);
  k_convgt<<<cgrid10, blk, 0, stream>>>(bufB, Wt3, b3, bufA);
  k_conv4t<<<cgrid20, blk, 0, stream>>>(bufA, Wt4, b4, bufB);
  k_fft<<<B_N * T_LEN, blk, 0, stream>>>(bufB, z, zwB);
  k_ola<<<B_N * T_LEN, blk, 0, stream>>>(zwB, (float*)d_out);
}

// Round 5
// 227.940 us; speedup vs baseline: 3.2360x; 1.1566x over previous
//
#include <hip/hip_runtime.h>

#define T_LEN 1000
#define B_N 8
#define IN_CH 80
#define CONV_CH 256
#define CCEP_N 222

__device__ __constant__ float STEP = 6.28318530717958647692f / 1024.f; // 2*pi/1024

// ===================== weight transpose kernels (run every call) ==============
__global__ __launch_bounds__(256) void k_tw1(const float* __restrict__ W,
                                             float* __restrict__ Wt) {
  int e = blockIdx.x * 256 + threadIdx.x;   // 61440
  int o = e / 240, k = e - o * 240;
  Wt[k * 256 + o] = W[e];
}
__global__ __launch_bounds__(256) void k_tw2(const float* __restrict__ W,
                                             float* __restrict__ Wt) {
  int e = blockIdx.x * 256 + threadIdx.x;   // 24576
  int o = e / 96, k = e - o * 96;
  Wt[k * 256 + o] = W[e];
}
// W4 (222,256,3) -> Wt4[k768][c224], scaled by 1/quef[c]
__global__ __launch_bounds__(256) void k_tw4(const float* __restrict__ W,
                                             float* __restrict__ Wt) {
  int e = blockIdx.x * 256 + threadIdx.x;   // 170496 = 222*768
  int c = e / 768, k = e - c * 768;
  float invq = 1.f / (float)((c < 111) ? (111 - c) : (c - 110));
  Wt[k * 224 + c] = W[e] * invq;
}

// ---------------- conv1: (B,T,80) -> (B,T,256), k=3 same, relu ----------------
// TT=10, staging pitch 14 (gcd(14,32)=2 -> free 2-way).
__global__ __launch_bounds__(256) void k_conv1t(const float* __restrict__ x,
    const float* __restrict__ Wt, const float* __restrict__ bias,
    float* __restrict__ out) {
  const int b = blockIdx.y;
  const int t0 = blockIdx.x * 10;
  const int o = threadIdx.x;
  __shared__ float hs[IN_CH * 14];
  for (int e = threadIdx.x; e < 12 * IN_CH; e += 256) {
    int r = e / IN_CH, c = e - r * IN_CH;
    int t = t0 - 1 + r;
    hs[c * 14 + r] = (t >= 0 && t < T_LEN) ? x[(b * T_LEN + t) * IN_CH + c] : 0.f;
  }
  __syncthreads();
  float acc[10];
  float bv = bias[o];
#pragma unroll
  for (int j = 0; j < 10; j++) acc[j] = bv;
  for (int i = 0; i < IN_CH; i++) {
    float w0 = Wt[(3 * i + 0) * 256 + o];
    float w1 = Wt[(3 * i + 1) * 256 + o];
    float w2 = Wt[(3 * i + 2) * 256 + o];
    const float* row = &hs[i * 14];
    float a[12];
#pragma unroll
    for (int u = 0; u < 6; u++) *(float2*)&a[2 * u] = *(const float2*)(row + 2 * u);
#pragma unroll
    for (int j = 0; j < 10; j++) {
      acc[j] = fmaf(a[j], w0, acc[j]);
      acc[j] = fmaf(a[j + 1], w1, acc[j]);
      acc[j] = fmaf(a[j + 2], w2, acc[j]);
    }
  }
#pragma unroll
  for (int j = 0; j < 10; j++)
    out[(b * T_LEN + t0 + j) * CONV_CH + o] = fmaxf(acc[j], 0.f);
}

// ------------- grouped conv: (B,T,256)->(B,T,256), groups=8, relu -------------
__global__ __launch_bounds__(256) void k_convgt(const float* __restrict__ h,
    const float* __restrict__ Wt, const float* __restrict__ bias,
    float* __restrict__ out) {
  const int b = blockIdx.y;
  const int t0 = blockIdx.x * 10;
  const int o = threadIdx.x;
  const int cb = (o >> 5) << 5;
  __shared__ float hs[CONV_CH * 14];
  for (int e = threadIdx.x; e < 12 * CONV_CH; e += 256) {
    int r = e >> 8, c = e & 255;
    int t = t0 - 1 + r;
    hs[c * 14 + r] = (t >= 0 && t < T_LEN) ? h[(b * T_LEN + t) * CONV_CH + c] : 0.f;
  }
  __syncthreads();
  float acc[10];
  float bv = bias[o];
#pragma unroll
  for (int j = 0; j < 10; j++) acc[j] = bv;
  for (int i = 0; i < 32; i++) {
    float w0 = Wt[(3 * i + 0) * 256 + o];
    float w1 = Wt[(3 * i + 1) * 256 + o];
    float w2 = Wt[(3 * i + 2) * 256 + o];
    const float* row = &hs[(cb + i) * 14];
    float a[12];
#pragma unroll
    for (int u = 0; u < 6; u++) *(float2*)&a[2 * u] = *(const float2*)(row + 2 * u);
#pragma unroll
    for (int j = 0; j < 10; j++) {
      acc[j] = fmaf(a[j], w0, acc[j]);
      acc[j] = fmaf(a[j + 1], w1, acc[j]);
      acc[j] = fmaf(a[j + 2], w2, acc[j]);
    }
  }
#pragma unroll
  for (int j = 0; j < 10; j++)
    out[(b * T_LEN + t0 + j) * CONV_CH + o] = fmaxf(acc[j], 0.f);
}

// -------- conv4: (B,T,256)->(B,T,222), quef folded into Wt4/bias --------------
// TT=8 (grid 1000 blocks), staging pitch 10 (2-way free).
__global__ __launch_bounds__(256) void k_conv4t(const float* __restrict__ h,
    const float* __restrict__ Wt, const float* __restrict__ bias,
    float* __restrict__ out) {
  const int b = blockIdx.y;
  const int t0 = blockIdx.x * 8;
  const int c = threadIdx.x;
  __shared__ float hs[CONV_CH * 10];
  for (int e = threadIdx.x; e < 10 * CONV_CH; e += 256) {
    int r = e >> 8, ci = e & 255;
    int t = t0 - 1 + r;
    hs[ci * 10 + r] = (t >= 0 && t < T_LEN) ? h[(b * T_LEN + t) * CONV_CH + ci] : 0.f;
  }
  __syncthreads();
  if (c >= CCEP_N) return;
  float invq = 1.f / (float)((c < 111) ? (111 - c) : (c - 110));
  float acc[8];
  float bv = bias[c] * invq;
#pragma unroll
  for (int j = 0; j < 8; j++) acc[j] = bv;
  for (int i = 0; i < CONV_CH; i++) {
    float w0 = Wt[(3 * i + 0) * 224 + c];
    float w1 = Wt[(3 * i + 1) * 224 + c];
    float w2 = Wt[(3 * i + 2) * 224 + c];
    const float* row = &hs[i * 10];
    float a[10];
#pragma unroll
    for (int u = 0; u < 5; u++) *(float2*)&a[2 * u] = *(const float2*)(row + 2 * u);
#pragma unroll
    for (int j = 0; j < 8; j++) {
      acc[j] = fmaf(a[j], w0, acc[j]);
      acc[j] = fmaf(a[j + 1], w1, acc[j]);
      acc[j] = fmaf(a[j + 2], w2, acc[j]);
    }
  }
#pragma unroll
  for (int j = 0; j < 8; j++)
    out[(b * T_LEN + t0 + j) * CCEP_N + c] = acc[j];
}

// ============================ fused FFT kernel ================================
// Pack W = c_pad + i*fr -> ONE 1024 DIF FFT (scrambled). Position p=4j+q holds
// natural k = q*256 + rev4d(j).  Partner of k = q*256 + r0:
//   r0==0: N-k = ((4-q)&3)*256            -> jp=0,              q' = (4-q)&3
//   r0> 0: N-k = (3-q)*256 + (256-r0)     -> jp=rev4d(256-r0),  q' = 3-q
__device__ __forceinline__ float2 cmul(float2 a, float2 b) {
  return make_float2(fmaf(a.x, b.x, -(a.y * b.y)), fmaf(a.x, b.y, a.y * b.x));
}
__device__ __forceinline__ float2 cadd(float2 a, float2 b) { return make_float2(a.x + b.x, a.y + b.y); }
__device__ __forceinline__ float2 csub(float2 a, float2 b) { return make_float2(a.x - b.x, a.y - b.y); }

#define LIDX(i) ((i) + ((i) >> 2))

template <int M>
__device__ __forceinline__ void fwd_stage(float2* __restrict__ X, int j) {
  constexpr int Q = M >> 2;
  const int pos = j & (Q - 1);
  const int base = ((j - pos) << 2) + pos;
  float s, c;
  __sincosf((6.28318530717958647692f / M) * (float)pos, &s, &c);
  const float2 w1 = make_float2(c, -s);
  const float2 w2 = cmul(w1, w1);
  const float2 w3 = cmul(w2, w1);
  float2 a = X[LIDX(base)], b = X[LIDX(base + Q)];
  float2 cc = X[LIDX(base + 2 * Q)], d = X[LIDX(base + 3 * Q)];
  float2 t0 = cadd(a, cc), t1 = csub(a, cc), t2 = cadd(b, d), bd = csub(b, d);
  float2 t3 = make_float2(bd.y, -bd.x);
  X[LIDX(base)]         = cadd(t0, t2);
  X[LIDX(base + Q)]     = cmul(cadd(t1, t3), w1);
  X[LIDX(base + 2 * Q)] = cmul(csub(t0, t2), w2);
  X[LIDX(base + 3 * Q)] = cmul(csub(t1, t3), w3);
}

template <int M>
__device__ __forceinline__ void inv_stage(float2* __restrict__ X, int j) {
  constexpr int Q = M >> 2;
  const int pos = j & (Q - 1);
  const int base = ((j - pos) << 2) + pos;
  float s, c;
  __sincosf((6.28318530717958647692f / M) * (float)pos, &s, &c);
  const float2 w1 = make_float2(c, s);
  const float2 w2 = cmul(w1, w1);
  const float2 w3 = cmul(w2, w1);
  float2 a = X[LIDX(base)];
  float2 b = cmul(X[LIDX(base + Q)], w1);
  float2 cc = cmul(X[LIDX(base + 2 * Q)], w2);
  float2 d = cmul(X[LIDX(base + 3 * Q)], w3);
  float2 t0 = cadd(a, cc), t1 = csub(a, cc), t2 = cadd(b, d), bd = csub(b, d);
  float2 t3 = make_float2(-bd.y, bd.x);
  X[LIDX(base)]         = cadd(t0, t2);
  X[LIDX(base + Q)]     = cadd(t1, t3);
  X[LIDX(base + 2 * Q)] = csub(t0, t2);
  X[LIDX(base + 3 * Q)] = csub(t1, t3);
}

__device__ __forceinline__ int rev4d(int v) {  // reverse four base-4 digits (8-bit)
  return ((v & 3) << 6) | (((v >> 2) & 3) << 4) | (((v >> 4) & 3) << 2) | ((v >> 6) & 3);
}

__global__ __launch_bounds__(256) void k_fft(const float* __restrict__ cc,
    const float* __restrict__ z, float* __restrict__ zw) {
  const int bt = blockIdx.x;
  const int b = bt / T_LEN, t = bt - b * T_LEN;
  const int j = threadIdx.x;
  __shared__ float2 Wl[1280];

  const float* zb = z + b * 256000;
#pragma unroll
  for (int r = 0; r < 4; ++r) {
    int p = j + 256 * r;
    float uv = 0.f;
    if (p >= 401 && p < 401 + CCEP_N) uv = cc[bt * CCEP_N + (p - 401)];
    float fv = 0.f;
    if (p < 512) {
      int zi = t * 256 + p - 255;
      if (zi >= 0 && zi < 256000) fv = zb[zi];
    }
    Wl[LIDX(p)] = make_float2(uv, fv);   // c + i*fr
  }
  __syncthreads();

  fwd_stage<1024>(Wl, j); __syncthreads();
  fwd_stage<256>(Wl, j);  __syncthreads();
  fwd_stage<64>(Wl, j);   __syncthreads();
  fwd_stage<16>(Wl, j);   __syncthreads();

  // fwd radix-4 (M=4, no twiddles) in registers; publish X to LDS
  const int base = 4 * j;
  float2 X[4];
  {
    float2 u0 = Wl[LIDX(base)], u1 = Wl[LIDX(base + 1)];
    float2 u2 = Wl[LIDX(base + 2)], u3 = Wl[LIDX(base + 3)];
    float2 t0 = cadd(u0, u2), t1 = csub(u0, u2), t2 = cadd(u1, u3), bd = csub(u1, u3);
    float2 t3 = make_float2(bd.y, -bd.x);
    X[0] = cadd(t0, t2); X[1] = cadd(t1, t3); X[2] = csub(t0, t2); X[3] = csub(t1, t3);
  }
  __syncthreads();   // everyone done reading Wl from fwd stages
#pragma unroll
  for (int q = 0; q < 4; ++q) Wl[LIDX(base + q)] = X[q];
  __syncthreads();

  // Hermitian unpack + pointwise + inverse radix-4 (registers)
  const int r0 = rev4d(j);
  const bool self0 = (r0 == 0);
  const int jp = self0 ? 0 : rev4d((256 - r0) & 255);
  float2 P[4];
#pragma unroll
  for (int q = 0; q < 4; ++q) P[q] = Wl[LIDX(4 * jp + q)];
  float2 S[4];
#pragma unroll
  for (int q = 0; q < 4; ++q) {
    float2 A = X[q];
    float2 Bc0 = P[(4 - q) & 3];   // partner sub-index when r0==0
    float2 Bc1 = P[3 - q];         // partner sub-index when r0> 0
    float2 Bc = self0 ? Bc0 : Bc1; // X[N-k]
    float2 Y = make_float2(0.5f * (A.x + Bc.x), 0.5f * (A.y - Bc.y));   // FFT(c)
    float2 F = make_float2(0.5f * (A.y + Bc.y), -0.5f * (A.x - Bc.x));  // FFT(fr)
    float mag = __expf(Y.x * 2.30258509299404568402f);  // 10^x
    float sy, cy;
    __sincosf(Y.y, &sy, &cy);
    float gr = mag * cy, gi = mag * sy;
    // S = conj(F)*G
    S[q] = make_float2(fmaf(F.x, gr, F.y * gi), fmaf(F.x, gi, -(F.y * gr)));
  }
  __syncthreads();   // all partner reads complete before overwrite
  {
    float2 t0 = cadd(S[0], S[2]), t1 = csub(S[0], S[2]), t2 = cadd(S[1], S[3]), bd = csub(S[1], S[3]);
    float2 t3 = make_float2(-bd.y, bd.x);
    Wl[LIDX(base)]     = cadd(t0, t2);
    Wl[LIDX(base + 1)] = cadd(t1, t3);
    Wl[LIDX(base + 2)] = csub(t0, t2);
    Wl[LIDX(base + 3)] = csub(t1, t3);
  }
  __syncthreads();

  inv_stage<16>(Wl, j);   __syncthreads();
  inv_stage<64>(Wl, j);   __syncthreads();
  inv_stage<256>(Wl, j);  __syncthreads();
  inv_stage<1024>(Wl, j); __syncthreads();

  const float ISC = 1.0f / 1024.0f;
  {
    int n = j;
    float cv = Wl[LIDX(511 - n)].x * ISC;
    float w = 0.5f - 0.5f * __cosf(STEP * 2.f * (float)n);
    zw[bt * 512 + n] = cv * w;
    n = j + 256;
    cv = Wl[LIDX(511 - n)].x * ISC;
    w = 0.5f - 0.5f * __cosf(STEP * 2.f * (float)n);
    zw[bt * 512 + n] = cv * w;
  }
}

// ---- overlap-add --------------------------------------------------------------
__global__ __launch_bounds__(256) void k_ola(const float* __restrict__ zw,
                                             float* __restrict__ out) {
  int idx = blockIdx.x * 256 + threadIdx.x;
  int j = idx & 255;
  int bt = idx >> 8;
  int t = bt % T_LEN;
  int btm = (t == 0) ? bt + (T_LEN - 1) : bt - 1;
  out[idx] = zw[bt * 512 + j] + zw[btm * 512 + 256 + j];
}

extern "C" void kernel_launch(void* const* d_in, const int* in_sizes, int n_in,
                              void* d_out, int out_size, void* d_ws, size_t ws_size,
                              hipStream_t stream) {
  const float* x  = (const float*)d_in[0];
  const float* z  = (const float*)d_in[1];
  const float* W1 = (const float*)d_in[2];
  const float* b1 = (const float*)d_in[3];
  const float* W2 = (const float*)d_in[4];
  const float* b2 = (const float*)d_in[5];
  const float* W3 = (const float*)d_in[6];
  const float* b3 = (const float*)d_in[7];
  const float* W4 = (const float*)d_in[8];
  const float* b4 = (const float*)d_in[9];

  float* ws   = (float*)d_ws;
  float* bufA = ws;                   // 2,048,000
  float* bufB = ws + 2048000;         // 2,048,000
  float* zwB  = ws + 4096000;         // 4,096,000
  float* Wt1  = ws + 8192000;         //    61,440
  float* Wt2  = ws + 8253440;         //    24,576
  float* Wt3  = ws + 8278016;         //    24,576
  float* Wt4  = ws + 8302592;         //   172,032

  dim3 blk(256);
  k_tw1<<<240, blk, 0, stream>>>(W1, Wt1);
  k_tw2<<<96,  blk, 0, stream>>>(W2, Wt2);
  k_tw2<<<96,  blk, 0, stream>>>(W3, Wt3);
  k_tw4<<<666, blk, 0, stream>>>(W4, Wt4);

  dim3 cgrid10(T_LEN / 10, B_N);  // (100, 8)
  dim3 cgrid8(T_LEN / 8, B_N);    // (125, 8)
  k_conv1t<<<cgrid10, blk, 0, stream>>>(x, Wt1, b1, bufA);
  k_convgt<<<cgrid10, blk, 0, stream>>>(bufA, Wt2, b2, bufB);
  k_convgt<<<cgrid10, blk, 0, stream>>>(bufB, Wt3, b3, bufA);
  k_conv4t<<<cgrid8, blk, 0, stream>>>(bufA, Wt4, b4, bufB);
  k_fft<<<B_N * T_LEN, blk, 0, stream>>>(bufB, z, zwB);
  k_ola<<<B_N * T_LEN, blk, 0, stream>>>(zwB, (float*)d_out);
}

// Round 6
// 219.316 us; speedup vs baseline: 3.3633x; 1.0393x over previous
//
#include <hip/hip_runtime.h>

#define T_LEN 1000
#define B_N 8
#define IN_CH 80
#define CONV_CH 256
#define CCEP_N 222

__device__ __constant__ float STEP = 6.28318530717958647692f / 1024.f; // 2*pi/1024

// ===================== weight transpose kernels (run every call) ==============
__global__ __launch_bounds__(256) void k_tw1(const float* __restrict__ W,
                                             float* __restrict__ Wt) {
  int e = blockIdx.x * 256 + threadIdx.x;   // 61440
  int o = e / 240, k = e - o * 240;
  Wt[k * 256 + o] = W[e];
}
__global__ __launch_bounds__(256) void k_tw2(const float* __restrict__ W,
                                             float* __restrict__ Wt) {
  int e = blockIdx.x * 256 + threadIdx.x;   // 24576
  int o = e / 96, k = e - o * 96;
  Wt[k * 256 + o] = W[e];
}
// W4 (222,256,3) -> Wt4[k768][c224], scaled by 1/quef[c]
__global__ __launch_bounds__(256) void k_tw4(const float* __restrict__ W,
                                             float* __restrict__ Wt) {
  int e = blockIdx.x * 256 + threadIdx.x;   // 170496 = 222*768
  int c = e / 768, k = e - c * 768;
  float invq = 1.f / (float)((c < 111) ? (111 - c) : (c - 110));
  Wt[k * 224 + c] = W[e] * invq;
}

// ---------------- conv1: (B,T,80) -> (B,T,256), k=3 same, relu ----------------
__global__ __launch_bounds__(256) void k_conv1t(const float* __restrict__ x,
    const float* __restrict__ Wt, const float* __restrict__ bias,
    float* __restrict__ out) {
  const int b = blockIdx.y;
  const int t0 = blockIdx.x * 10;
  const int o = threadIdx.x;
  __shared__ float hs[IN_CH * 14];
  for (int e = threadIdx.x; e < 12 * IN_CH; e += 256) {
    int r = e / IN_CH, c = e - r * IN_CH;
    int t = t0 - 1 + r;
    hs[c * 14 + r] = (t >= 0 && t < T_LEN) ? x[(b * T_LEN + t) * IN_CH + c] : 0.f;
  }
  __syncthreads();
  float acc[10];
  float bv = bias[o];
#pragma unroll
  for (int j = 0; j < 10; j++) acc[j] = bv;
  for (int i = 0; i < IN_CH; i++) {
    float w0 = Wt[(3 * i + 0) * 256 + o];
    float w1 = Wt[(3 * i + 1) * 256 + o];
    float w2 = Wt[(3 * i + 2) * 256 + o];
    const float* row = &hs[i * 14];
    float a[12];
#pragma unroll
    for (int u = 0; u < 6; u++) *(float2*)&a[2 * u] = *(const float2*)(row + 2 * u);
#pragma unroll
    for (int j = 0; j < 10; j++) {
      acc[j] = fmaf(a[j], w0, acc[j]);
      acc[j] = fmaf(a[j + 1], w1, acc[j]);
      acc[j] = fmaf(a[j + 2], w2, acc[j]);
    }
  }
#pragma unroll
  for (int j = 0; j < 10; j++)
    out[(b * T_LEN + t0 + j) * CONV_CH + o] = fmaxf(acc[j], 0.f);
}

// ------------- grouped conv: (B,T,256)->(B,T,256), groups=8, relu -------------
__global__ __launch_bounds__(256) void k_convgt(const float* __restrict__ h,
    const float* __restrict__ Wt, const float* __restrict__ bias,
    float* __restrict__ out) {
  const int b = blockIdx.y;
  const int t0 = blockIdx.x * 10;
  const int o = threadIdx.x;
  const int cb = (o >> 5) << 5;
  __shared__ float hs[CONV_CH * 14];
  for (int e = threadIdx.x; e < 12 * CONV_CH; e += 256) {
    int r = e >> 8, c = e & 255;
    int t = t0 - 1 + r;
    hs[c * 14 + r] = (t >= 0 && t < T_LEN) ? h[(b * T_LEN + t) * CONV_CH + c] : 0.f;
  }
  __syncthreads();
  float acc[10];
  float bv = bias[o];
#pragma unroll
  for (int j = 0; j < 10; j++) acc[j] = bv;
  for (int i = 0; i < 32; i++) {
    float w0 = Wt[(3 * i + 0) * 256 + o];
    float w1 = Wt[(3 * i + 1) * 256 + o];
    float w2 = Wt[(3 * i + 2) * 256 + o];
    const float* row = &hs[(cb + i) * 14];
    float a[12];
#pragma unroll
    for (int u = 0; u < 6; u++) *(float2*)&a[2 * u] = *(const float2*)(row + 2 * u);
#pragma unroll
    for (int j = 0; j < 10; j++) {
      acc[j] = fmaf(a[j], w0, acc[j]);
      acc[j] = fmaf(a[j + 1], w1, acc[j]);
      acc[j] = fmaf(a[j + 2], w2, acc[j]);
    }
  }
#pragma unroll
  for (int j = 0; j < 10; j++)
    out[(b * T_LEN + t0 + j) * CONV_CH + o] = fmaxf(acc[j], 0.f);
}

// -------- conv4 K-split: (B,T,256)->(B,T,222) partials over half the in-chans -
// grid (125, 8, 2); blockIdx.z selects input-channel half; TT=8, pitch 10.
__global__ __launch_bounds__(256) void k_conv4s(const float* __restrict__ h,
    const float* __restrict__ Wt, const float* __restrict__ bias,
    float* __restrict__ P) {
  const int ks = blockIdx.z;
  const int b = blockIdx.y;
  const int t0 = blockIdx.x * 8;
  const int c = threadIdx.x;
  __shared__ float hs[128 * 10];
  for (int e = threadIdx.x; e < 1280; e += 256) {
    int r = e >> 7, ci = e & 127;
    int t = t0 - 1 + r;
    hs[ci * 10 + r] = (t >= 0 && t < T_LEN)
        ? h[(b * T_LEN + t) * CONV_CH + ks * 128 + ci] : 0.f;
  }
  __syncthreads();
  if (c >= CCEP_N) return;
  float acc[8];
  float bv = 0.f;
  if (ks == 0) {
    float invq = 1.f / (float)((c < 111) ? (111 - c) : (c - 110));
    bv = bias[c] * invq;
  }
#pragma unroll
  for (int j = 0; j < 8; j++) acc[j] = bv;
  const float* Wk = Wt + (3 * ks * 128) * 224;
  for (int i = 0; i < 128; i++) {
    float w0 = Wk[(3 * i + 0) * 224 + c];
    float w1 = Wk[(3 * i + 1) * 224 + c];
    float w2 = Wk[(3 * i + 2) * 224 + c];
    const float* row = &hs[i * 10];
    float a[10];
#pragma unroll
    for (int u = 0; u < 5; u++) *(float2*)&a[2 * u] = *(const float2*)(row + 2 * u);
#pragma unroll
    for (int j = 0; j < 8; j++) {
      acc[j] = fmaf(a[j], w0, acc[j]);
      acc[j] = fmaf(a[j + 1], w1, acc[j]);
      acc[j] = fmaf(a[j + 2], w2, acc[j]);
    }
  }
  float* Pp = P + ks * 1776000;
#pragma unroll
  for (int j = 0; j < 8; j++)
    Pp[(b * T_LEN + t0 + j) * CCEP_N + c] = acc[j];
}

// ============================ fused FFT kernel ================================
// Pack W = c_pad + i*fr -> ONE 1024 DIF FFT (scrambled). Position p=4j+q holds
// natural k = q*256 + rev4d(j).  Partner of k = q*256 + r0:
//   r0==0: q' = (4-q)&3, jp=0;  r0>0: q' = 3-q, jp=rev4d(256-r0)
// First fwd stage computed from global loads in registers (inputs sparse);
// last inv stage inlined (only Re of outputs j, j+256 needed -> zw[511-j],
// zw[255-j] directly).  cc = P0 + P1 (conv4 K-split partials).
__device__ __forceinline__ float2 cmul(float2 a, float2 b) {
  return make_float2(fmaf(a.x, b.x, -(a.y * b.y)), fmaf(a.x, b.y, a.y * b.x));
}
__device__ __forceinline__ float2 cadd(float2 a, float2 b) { return make_float2(a.x + b.x, a.y + b.y); }
__device__ __forceinline__ float2 csub(float2 a, float2 b) { return make_float2(a.x - b.x, a.y - b.y); }

#define LIDX(i) ((i) + ((i) >> 2))

template <int M>
__device__ __forceinline__ void fwd_stage(float2* __restrict__ X, int j) {
  constexpr int Q = M >> 2;
  const int pos = j & (Q - 1);
  const int base = ((j - pos) << 2) + pos;
  float s, c;
  __sincosf((6.28318530717958647692f / M) * (float)pos, &s, &c);
  const float2 w1 = make_float2(c, -s);
  const float2 w2 = cmul(w1, w1);
  const float2 w3 = cmul(w2, w1);
  float2 a = X[LIDX(base)], b = X[LIDX(base + Q)];
  float2 cc = X[LIDX(base + 2 * Q)], d = X[LIDX(base + 3 * Q)];
  float2 t0 = cadd(a, cc), t1 = csub(a, cc), t2 = cadd(b, d), bd = csub(b, d);
  float2 t3 = make_float2(bd.y, -bd.x);
  X[LIDX(base)]         = cadd(t0, t2);
  X[LIDX(base + Q)]     = cmul(cadd(t1, t3), w1);
  X[LIDX(base + 2 * Q)] = cmul(csub(t0, t2), w2);
  X[LIDX(base + 3 * Q)] = cmul(csub(t1, t3), w3);
}

template <int M>
__device__ __forceinline__ void inv_stage(float2* __restrict__ X, int j) {
  constexpr int Q = M >> 2;
  const int pos = j & (Q - 1);
  const int base = ((j - pos) << 2) + pos;
  float s, c;
  __sincosf((6.28318530717958647692f / M) * (float)pos, &s, &c);
  const float2 w1 = make_float2(c, s);
  const float2 w2 = cmul(w1, w1);
  const float2 w3 = cmul(w2, w1);
  float2 a = X[LIDX(base)];
  float2 b = cmul(X[LIDX(base + Q)], w1);
  float2 cc = cmul(X[LIDX(base + 2 * Q)], w2);
  float2 d = cmul(X[LIDX(base + 3 * Q)], w3);
  float2 t0 = cadd(a, cc), t1 = csub(a, cc), t2 = cadd(b, d), bd = csub(b, d);
  float2 t3 = make_float2(-bd.y, bd.x);
  X[LIDX(base)]         = cadd(t0, t2);
  X[LIDX(base + Q)]     = cadd(t1, t3);
  X[LIDX(base + 2 * Q)] = csub(t0, t2);
  X[LIDX(base + 3 * Q)] = csub(t1, t3);
}

__device__ __forceinline__ int rev4d(int v) {  // reverse four base-4 digits (8-bit)
  return ((v & 3) << 6) | (((v >> 2) & 3) << 4) | (((v >> 4) & 3) << 2) | ((v >> 6) & 3);
}

__global__ __launch_bounds__(256) void k_fft(const float* __restrict__ P0,
    const float* __restrict__ P1, const float* __restrict__ z,
    float* __restrict__ zw) {
  const int bt = blockIdx.x;
  const int b = bt / T_LEN, t = bt - b * T_LEN;
  const int j = threadIdx.x;
  __shared__ float2 Wl[1280];

  // ---- first forward stage (M=1024) straight from global, sparse inputs ----
  // natural p=j+256r: x0=(0,f0), x1=(c1,f1), x2=(c2,0), x3=(0,0)
  const float* zb = z + b * 256000;
  float f0 = 0.f, f1 = 0.f, c1 = 0.f, c2 = 0.f;
  {
    int zi0 = t * 256 + j - 255;
    if (zi0 >= 0) f0 = zb[zi0];
    int zi1 = t * 256 + j + 1;
    if (zi1 < 256000) f1 = zb[zi1];
    if (j >= 145) { int m = j - 145; c1 = P0[bt * CCEP_N + m] + P1[bt * CCEP_N + m]; }
    if (j < 111)  { int m = j + 111; c2 = P0[bt * CCEP_N + m] + P1[bt * CCEP_N + m]; }
  }
  {
    float sw, cw;
    __sincosf(STEP * (float)j, &sw, &cw);
    const float2 w1 = make_float2(cw, -sw);
    const float2 w2 = cmul(w1, w1);
    const float2 w3 = cmul(w2, w1);
    float2 t0 = make_float2(c2, f0);          // x0+x2
    float2 t1 = make_float2(-c2, f0);         // x0-x2
    float2 t2 = make_float2(c1, f1);          // x1+x3
    float2 t3 = make_float2(f1, -c1);         // -i*(x1-x3)
    Wl[LIDX(j)]       = cadd(t0, t2);
    Wl[LIDX(j + 256)] = cmul(cadd(t1, t3), w1);
    Wl[LIDX(j + 512)] = cmul(csub(t0, t2), w2);
    Wl[LIDX(j + 768)] = cmul(csub(t1, t3), w3);
  }
  __syncthreads();

  fwd_stage<256>(Wl, j);  __syncthreads();
  fwd_stage<64>(Wl, j);   __syncthreads();
  fwd_stage<16>(Wl, j);   __syncthreads();

  // fwd radix-4 (M=4, no twiddles) in registers; publish X to LDS
  const int base = 4 * j;
  float2 X[4];
  {
    float2 u0 = Wl[LIDX(base)], u1 = Wl[LIDX(base + 1)];
    float2 u2 = Wl[LIDX(base + 2)], u3 = Wl[LIDX(base + 3)];
    float2 t0 = cadd(u0, u2), t1 = csub(u0, u2), t2 = cadd(u1, u3), bd = csub(u1, u3);
    float2 t3 = make_float2(bd.y, -bd.x);
    X[0] = cadd(t0, t2); X[1] = cadd(t1, t3); X[2] = csub(t0, t2); X[3] = csub(t1, t3);
  }
#pragma unroll
  for (int q = 0; q < 4; ++q) Wl[LIDX(base + q)] = X[q];
  __syncthreads();

  // Hermitian unpack + pointwise + inverse radix-4 (registers)
  const int r0 = rev4d(j);
  const bool self0 = (r0 == 0);
  const int jp = self0 ? 0 : rev4d((256 - r0) & 255);
  float2 P[4];
#pragma unroll
  for (int q = 0; q < 4; ++q) P[q] = Wl[LIDX(4 * jp + q)];
  float2 S[4];
#pragma unroll
  for (int q = 0; q < 4; ++q) {
    float2 A = X[q];
    float2 Bc0 = P[(4 - q) & 3];   // partner sub-index when r0==0
    float2 Bc1 = P[3 - q];         // partner sub-index when r0> 0
    float2 Bc = self0 ? Bc0 : Bc1; // X[N-k]
    float2 Y = make_float2(0.5f * (A.x + Bc.x), 0.5f * (A.y - Bc.y));   // FFT(c)
    float2 F = make_float2(0.5f * (A.y + Bc.y), -0.5f * (A.x - Bc.x));  // FFT(fr)
    float mag = __expf(Y.x * 2.30258509299404568402f);  // 10^x
    float sy, cy;
    __sincosf(Y.y, &sy, &cy);
    float gr = mag * cy, gi = mag * sy;
    S[q] = make_float2(fmaf(F.x, gr, F.y * gi), fmaf(F.x, gi, -(F.y * gr)));
  }
  __syncthreads();   // all partner reads complete before overwrite
  {
    float2 t0 = cadd(S[0], S[2]), t1 = csub(S[0], S[2]), t2 = cadd(S[1], S[3]), bd = csub(S[1], S[3]);
    float2 t3 = make_float2(-bd.y, bd.x);
    Wl[LIDX(base)]     = cadd(t0, t2);
    Wl[LIDX(base + 1)] = cadd(t1, t3);
    Wl[LIDX(base + 2)] = csub(t0, t2);
    Wl[LIDX(base + 3)] = csub(t1, t3);
  }
  __syncthreads();

  inv_stage<16>(Wl, j);   __syncthreads();
  inv_stage<64>(Wl, j);   __syncthreads();
  inv_stage<256>(Wl, j);  __syncthreads();

  // ---- final inverse stage (M=1024) inlined: need only Re(C[j]), Re(C[j+256])
  {
    float sw, cw;
    __sincosf(STEP * (float)j, &sw, &cw);
    // conj twiddles: w1=(cw,sw), w2=w1^2, w3=w2*w1
    float w2x = fmaf(cw, cw, -(sw * sw)), w2y = 2.f * cw * sw;
    float w3x = fmaf(w2x, cw, -(w2y * sw)), w3y = fmaf(w2x, sw, w2y * cw);
    float2 A = Wl[LIDX(j)];
    float2 B = Wl[LIDX(j + 256)];
    float2 C2 = Wl[LIDX(j + 512)];
    float2 D = Wl[LIDX(j + 768)];
    float bx = fmaf(B.x, cw, -(B.y * sw)), by = fmaf(B.x, sw, B.y * cw);
    float cx = fmaf(C2.x, w2x, -(C2.y * w2y));
    float dx = fmaf(D.x, w3x, -(D.y * w3y)), dy = fmaf(D.x, w3y, D.y * w3x);
    float cj    = (A.x + cx) + (bx + dx);          // Re(C[j])
    float cj256 = (A.x - cx) - (by - dy);          // Re(C[j+256])
    const float ISC = 1.0f / 1024.0f;
    int n1 = 511 - j, n2 = 255 - j;
    float wn1 = 0.5f - 0.5f * __cosf(STEP * 2.f * (float)n1);
    float wn2 = 0.5f - 0.5f * __cosf(STEP * 2.f * (float)n2);
    zw[bt * 512 + n1] = cj * ISC * wn1;
    zw[bt * 512 + n2] = cj256 * ISC * wn2;
  }
}

// ---- overlap-add --------------------------------------------------------------
__global__ __launch_bounds__(256) void k_ola(const float* __restrict__ zw,
                                             float* __restrict__ out) {
  int idx = blockIdx.x * 256 + threadIdx.x;
  int j = idx & 255;
  int bt = idx >> 8;
  int t = bt % T_LEN;
  int btm = (t == 0) ? bt + (T_LEN - 1) : bt - 1;
  out[idx] = zw[bt * 512 + j] + zw[btm * 512 + 256 + j];
}

extern "C" void kernel_launch(void* const* d_in, const int* in_sizes, int n_in,
                              void* d_out, int out_size, void* d_ws, size_t ws_size,
                              hipStream_t stream) {
  const float* x  = (const float*)d_in[0];
  const float* z  = (const float*)d_in[1];
  const float* W1 = (const float*)d_in[2];
  const float* b1 = (const float*)d_in[3];
  const float* W2 = (const float*)d_in[4];
  const float* b2 = (const float*)d_in[5];
  const float* W3 = (const float*)d_in[6];
  const float* b3 = (const float*)d_in[7];
  const float* W4 = (const float*)d_in[8];
  const float* b4 = (const float*)d_in[9];

  float* ws   = (float*)d_ws;
  float* bufA = ws;                    // 2,048,000
  float* bufC = ws + 2048000;          // 2,048,000
  float* P0   = ws + 4096000;          // 1,776,000
  float* P1   = ws + 5872000;          // 1,776,000 (P0 + ks*1776000)
  float* zwB  = ws + 7648000;          // 4,096,000
  float* Wt1  = ws + 11744000;         //    61,440
  float* Wt2  = ws + 11805440;         //    24,576
  float* Wt3  = ws + 11830016;         //    24,576
  float* Wt4  = ws + 11854592;         //   172,032  (end 12,026,624 f32 = 48 MB)

  dim3 blk(256);
  k_tw1<<<240, blk, 0, stream>>>(W1, Wt1);
  k_tw2<<<96,  blk, 0, stream>>>(W2, Wt2);
  k_tw2<<<96,  blk, 0, stream>>>(W3, Wt3);
  k_tw4<<<666, blk, 0, stream>>>(W4, Wt4);

  dim3 cgrid10(T_LEN / 10, B_N);     // (100, 8)
  dim3 cgrid8s(T_LEN / 8, B_N, 2);   // (125, 8, 2)
  k_conv1t<<<cgrid10, blk, 0, stream>>>(x, Wt1, b1, bufA);
  k_convgt<<<cgrid10, blk, 0, stream>>>(bufA, Wt2, b2, bufC);
  k_convgt<<<cgrid10, blk, 0, stream>>>(bufC, Wt3, b3, bufA);
  k_conv4s<<<cgrid8s, blk, 0, stream>>>(bufA, Wt4, b4, P0);
  k_fft<<<B_N * T_LEN, blk, 0, stream>>>(P0, P1, z, zwB);
  k_ola<<<B_N * T_LEN, blk, 0, stream>>>(zwB, (float*)d_out);
}

// Round 7
// 185.406 us; speedup vs baseline: 3.9784x; 1.1829x over previous
//
#include <hip/hip_runtime.h>
#include <hip/hip_bf16.h>

#define T_LEN 1000
#define B_N 8
#define IN_CH 80
#define CONV_CH 256
#define CCEP_N 222

typedef short s8v __attribute__((ext_vector_type(8)));    // 8 bf16 (4 VGPRs)
typedef float f16v __attribute__((ext_vector_type(16)));  // MFMA 32x32 acc

__device__ __constant__ float STEP = 6.28318530717958647692f / 1024.f; // 2*pi/1024

// ===================== weight prep kernels (run every call) ===================
__global__ __launch_bounds__(256) void k_tw1(const float* __restrict__ W,
                                             float* __restrict__ Wt) {
  int e = blockIdx.x * 256 + threadIdx.x;   // 61440
  int o = e / 240, k = e - o * 240;
  Wt[k * 256 + o] = W[e];
}
__global__ __launch_bounds__(256) void k_tw2(const float* __restrict__ W,
                                             float* __restrict__ Wt) {
  int e = blockIdx.x * 256 + threadIdx.x;   // 24576
  int o = e / 96, k = e - o * 96;
  Wt[k * 256 + o] = W[e];
}
// W4 (222,256,3) -> Wc chunked bf16: [chg 0..23][n 0..255][kloc 0..31],
// k' = chg*32+kloc = kappa*256+i, quef folded, n>=222 zero.
__global__ __launch_bounds__(256) void k_tw4c(const float* __restrict__ W,
                                              __hip_bfloat16* __restrict__ Wc) {
  int e = blockIdx.x * 256 + threadIdx.x;   // 196608
  int kloc = e & 31, n = (e >> 5) & 255, chg = e >> 13;
  int kp = chg * 32 + kloc;
  int kappa = kp >> 8, i = kp & 255;
  float v = 0.f;
  if (n < CCEP_N) {
    float invq = 1.f / (float)((n < 111) ? (111 - n) : (n - 110));
    v = W[n * 768 + i * 3 + kappa] * invq;
  }
  Wc[e] = __float2bfloat16(v);
}

// ---------------- conv1: (B,T,80) -> (B,T,256), k=3 same, relu ----------------
__global__ __launch_bounds__(256) void k_conv1t(const float* __restrict__ x,
    const float* __restrict__ Wt, const float* __restrict__ bias,
    float* __restrict__ out) {
  const int b = blockIdx.y;
  const int t0 = blockIdx.x * 10;
  const int o = threadIdx.x;
  __shared__ float hs[IN_CH * 14];
  for (int e = threadIdx.x; e < 12 * IN_CH; e += 256) {
    int r = e / IN_CH, c = e - r * IN_CH;
    int t = t0 - 1 + r;
    hs[c * 14 + r] = (t >= 0 && t < T_LEN) ? x[(b * T_LEN + t) * IN_CH + c] : 0.f;
  }
  __syncthreads();
  float acc[10];
  float bv = bias[o];
#pragma unroll
  for (int j = 0; j < 10; j++) acc[j] = bv;
  for (int i = 0; i < IN_CH; i++) {
    float w0 = Wt[(3 * i + 0) * 256 + o];
    float w1 = Wt[(3 * i + 1) * 256 + o];
    float w2 = Wt[(3 * i + 2) * 256 + o];
    const float* row = &hs[i * 14];
    float a[12];
#pragma unroll
    for (int u = 0; u < 6; u++) *(float2*)&a[2 * u] = *(const float2*)(row + 2 * u);
#pragma unroll
    for (int j = 0; j < 10; j++) {
      acc[j] = fmaf(a[j], w0, acc[j]);
      acc[j] = fmaf(a[j + 1], w1, acc[j]);
      acc[j] = fmaf(a[j + 2], w2, acc[j]);
    }
  }
#pragma unroll
  for (int j = 0; j < 10; j++)
    out[(b * T_LEN + t0 + j) * CONV_CH + o] = fmaxf(acc[j], 0.f);
}

// ------------- grouped conv: (B,T,256)->(B,T,256), groups=8, relu -------------
__global__ __launch_bounds__(256) void k_convgt(const float* __restrict__ h,
    const float* __restrict__ Wt, const float* __restrict__ bias,
    float* __restrict__ out) {
  const int b = blockIdx.y;
  const int t0 = blockIdx.x * 10;
  const int o = threadIdx.x;
  const int cb = (o >> 5) << 5;
  __shared__ float hs[CONV_CH * 14];
  for (int e = threadIdx.x; e < 12 * CONV_CH; e += 256) {
    int r = e >> 8, c = e & 255;
    int t = t0 - 1 + r;
    hs[c * 14 + r] = (t >= 0 && t < T_LEN) ? h[(b * T_LEN + t) * CONV_CH + c] : 0.f;
  }
  __syncthreads();
  float acc[10];
  float bv = bias[o];
#pragma unroll
  for (int j = 0; j < 10; j++) acc[j] = bv;
  for (int i = 0; i < 32; i++) {
    float w0 = Wt[(3 * i + 0) * 256 + o];
    float w1 = Wt[(3 * i + 1) * 256 + o];
    float w2 = Wt[(3 * i + 2) * 256 + o];
    const float* row = &hs[(cb + i) * 14];
    float a[12];
#pragma unroll
    for (int u = 0; u < 6; u++) *(float2*)&a[2 * u] = *(const float2*)(row + 2 * u);
#pragma unroll
    for (int j = 0; j < 10; j++) {
      acc[j] = fmaf(a[j], w0, acc[j]);
      acc[j] = fmaf(a[j + 1], w1, acc[j]);
      acc[j] = fmaf(a[j + 2], w2, acc[j]);
    }
  }
#pragma unroll
  for (int j = 0; j < 10; j++)
    out[(b * T_LEN + t0 + j) * CONV_CH + o] = fmaxf(acc[j], 0.f);
}

// ------------- grouped conv variant writing bf16 (h3 feeds MFMA conv4) --------
__global__ __launch_bounds__(256) void k_convgt_b(const float* __restrict__ h,
    const float* __restrict__ Wt, const float* __restrict__ bias,
    __hip_bfloat16* __restrict__ out) {
  const int b = blockIdx.y;
  const int t0 = blockIdx.x * 10;
  const int o = threadIdx.x;
  const int cb = (o >> 5) << 5;
  __shared__ float hs[CONV_CH * 14];
  for (int e = threadIdx.x; e < 12 * CONV_CH; e += 256) {
    int r = e >> 8, c = e & 255;
    int t = t0 - 1 + r;
    hs[c * 14 + r] = (t >= 0 && t < T_LEN) ? h[(b * T_LEN + t) * CONV_CH + c] : 0.f;
  }
  __syncthreads();
  float acc[10];
  float bv = bias[o];
#pragma unroll
  for (int j = 0; j < 10; j++) acc[j] = bv;
  for (int i = 0; i < 32; i++) {
    float w0 = Wt[(3 * i + 0) * 256 + o];
    float w1 = Wt[(3 * i + 1) * 256 + o];
    float w2 = Wt[(3 * i + 2) * 256 + o];
    const float* row = &hs[(cb + i) * 14];
    float a[12];
#pragma unroll
    for (int u = 0; u < 6; u++) *(float2*)&a[2 * u] = *(const float2*)(row + 2 * u);
#pragma unroll
    for (int j = 0; j < 10; j++) {
      acc[j] = fmaf(a[j], w0, acc[j]);
      acc[j] = fmaf(a[j + 1], w1, acc[j]);
      acc[j] = fmaf(a[j + 2], w2, acc[j]);
    }
  }
#pragma unroll
  for (int j = 0; j < 10; j++)
    out[(b * T_LEN + t0 + j) * CONV_CH + o] = __float2bfloat16(fmaxf(acc[j], 0.f));
}

// ============ conv4 as MFMA GEMM: C[8000,222] = A[8000,768] x B[768,222] ======
#define APITCH 264   // bf16 elems; 132 words = 4 mod 32 -> even b128 banks
#define BPITCH 40    // 20 words = 20 mod 32 -> even b128 banks
__global__ __launch_bounds__(256) void k_conv4m(
    const __hip_bfloat16* __restrict__ h3, const __hip_bfloat16* __restrict__ Wc,
    const float* __restrict__ bias, float* __restrict__ Pbase) {
  const int mb = blockIdx.x, b = blockIdx.y, ks = blockIdx.z;
  float* __restrict__ P = Pbase + (size_t)ks * 1792000;
  const int t0 = mb * 64;
  const int tid = threadIdx.x;
  const int w = tid >> 6, lane = tid & 63;
  const int wm = w >> 1, wn = w & 1;
  const int lm = lane & 31, half = lane >> 5;

  __shared__ short h3s[67 * APITCH];
  __shared__ short Bs[2][256 * BPITCH];

  const ushort* h3u = (const ushort*)h3;
  for (int g = tid; g < 67 * 64; g += 256) {
    int rr = g >> 6, c4 = g & 63;
    int t = t0 + rr - 1;
    uint2 v = make_uint2(0u, 0u);
    if (t >= 0 && t < T_LEN)
      v = *(const uint2*)(h3u + (b * T_LEN + t) * CONV_CH + c4 * 4);
    *(uint2*)(h3s + rr * APITCH + c4 * 4) = v;
  }

  const ushort* Wu = (const ushort*)(Wc) + (size_t)(ks * 12) * 8192;
#pragma unroll
  for (int it = 0; it < 4; ++it) {
    int idx = (it * 256 + tid) * 8;
    uint4 v = *(const uint4*)(Wu + idx);
    int n = idx >> 5, kloc = idx & 31;
    *(uint4*)(Bs[0] + n * BPITCH + kloc) = v;
  }
  __syncthreads();

  f16v acc0 = {}, acc1 = {}, acc2 = {}, acc3 = {};

  for (int ch = 0; ch < 12; ++ch) {
    const int p = ch & 1;
    if (ch < 11) {
      const ushort* src = Wu + (ch + 1) * 8192;
#pragma unroll
      for (int it = 0; it < 4; ++it) {
        int idx = (it * 256 + tid) * 8;
        uint4 v = *(const uint4*)(src + idx);
        int n = idx >> 5, kloc = idx & 31;
        *(uint4*)(Bs[p ^ 1] + n * BPITCH + kloc) = v;
      }
    }
#pragma unroll
    for (int s = 0; s < 2; ++s) {
      int k0 = ks * 384 + ch * 32 + s * 16;
      int kappa = k0 >> 8, i0 = k0 & 255;
      s8v a = *(const s8v*)(h3s + (wm * 32 + lm + kappa) * APITCH + i0 + half * 8);
      const short* bp = Bs[p] + (wn * 128 + lm) * BPITCH + s * 16 + half * 8;
      s8v b0 = *(const s8v*)(bp);
      s8v b1 = *(const s8v*)(bp + 32 * BPITCH);
      s8v b2 = *(const s8v*)(bp + 64 * BPITCH);
      s8v b3 = *(const s8v*)(bp + 96 * BPITCH);
      acc0 = __builtin_amdgcn_mfma_f32_32x32x16_bf16(a, b0, acc0, 0, 0, 0);
      acc1 = __builtin_amdgcn_mfma_f32_32x32x16_bf16(a, b1, acc1, 0, 0, 0);
      acc2 = __builtin_amdgcn_mfma_f32_32x32x16_bf16(a, b2, acc2, 0, 0, 0);
      acc3 = __builtin_amdgcn_mfma_f32_32x32x16_bf16(a, b3, acc3, 0, 0, 0);
    }
    __syncthreads();
  }

  const int col = lm;
#pragma unroll
  for (int nt = 0; nt < 4; ++nt) {
    int c = wn * 128 + nt * 32 + col;
    if (c >= CCEP_N) continue;
    float bq = 0.f;
    if (ks == 0) {
      float invq = 1.f / (float)((c < 111) ? (111 - c) : (c - 110));
      bq = bias[c] * invq;
    }
    const f16v* A = (nt == 0) ? &acc0 : (nt == 1) ? &acc1 : (nt == 2) ? &acc2 : &acc3;
#pragma unroll
    for (int reg = 0; reg < 16; ++reg) {
      int row = (reg & 3) + 8 * (reg >> 2) + 4 * half;
      int t = t0 + wm * 32 + row;
      if (t < T_LEN)
        P[(size_t)(b * T_LEN + t) * 224 + c] = (*A)[reg] + bq;
    }
  }
}

// ============================ fused FFT kernel ================================
__device__ __forceinline__ float2 cmul(float2 a, float2 b) {
  return make_float2(fmaf(a.x, b.x, -(a.y * b.y)), fmaf(a.x, b.y, a.y * b.x));
}
__device__ __forceinline__ float2 cadd(float2 a, float2 b) { return make_float2(a.x + b.x, a.y + b.y); }
__device__ __forceinline__ float2 csub(float2 a, float2 b) { return make_float2(a.x - b.x, a.y - b.y); }

#define LIDX(i) ((i) + ((i) >> 2))

template <int M>
__device__ __forceinline__ void fwd_stage(float2* __restrict__ X, int j) {
  constexpr int Q = M >> 2;
  const int pos = j & (Q - 1);
  const int base = ((j - pos) << 2) + pos;
  float s, c;
  __sincosf((6.28318530717958647692f / M) * (float)pos, &s, &c);
  const float2 w1 = make_float2(c, -s);
  const float2 w2 = cmul(w1, w1);
  const float2 w3 = cmul(w2, w1);
  float2 a = X[LIDX(base)], b = X[LIDX(base + Q)];
  float2 cc = X[LIDX(base + 2 * Q)], d = X[LIDX(base + 3 * Q)];
  float2 t0 = cadd(a, cc), t1 = csub(a, cc), t2 = cadd(b, d), bd = csub(b, d);
  float2 t3 = make_float2(bd.y, -bd.x);
  X[LIDX(base)]         = cadd(t0, t2);
  X[LIDX(base + Q)]     = cmul(cadd(t1, t3), w1);
  X[LIDX(base + 2 * Q)] = cmul(csub(t0, t2), w2);
  X[LIDX(base + 3 * Q)] = cmul(csub(t1, t3), w3);
}

template <int M>
__device__ __forceinline__ void inv_stage(float2* __restrict__ X, int j) {
  constexpr int Q = M >> 2;
  const int pos = j & (Q - 1);
  const int base = ((j - pos) << 2) + pos;
  float s, c;
  __sincosf((6.28318530717958647692f / M) * (float)pos, &s, &c);
  const float2 w1 = make_float2(c, s);
  const float2 w2 = cmul(w1, w1);
  const float2 w3 = cmul(w2, w1);
  float2 a = X[LIDX(base)];
  float2 b = cmul(X[LIDX(base + Q)], w1);
  float2 cc = cmul(X[LIDX(base + 2 * Q)], w2);
  float2 d = cmul(X[LIDX(base + 3 * Q)], w3);
  float2 t0 = cadd(a, cc), t1 = csub(a, cc), t2 = cadd(b, d), bd = csub(b, d);
  float2 t3 = make_float2(-bd.y, bd.x);
  X[LIDX(base)]         = cadd(t0, t2);
  X[LIDX(base + Q)]     = cadd(t1, t3);
  X[LIDX(base + 2 * Q)] = csub(t0, t2);
  X[LIDX(base + 3 * Q)] = csub(t1, t3);
}

__device__ __forceinline__ int rev4d(int v) {
  return ((v & 3) << 6) | (((v >> 2) & 3) << 4) | (((v >> 4) & 3) << 2) | ((v >> 6) & 3);
}

__global__ __launch_bounds__(256) void k_fft(const float* __restrict__ P0,
    const float* __restrict__ P1, const float* __restrict__ z,
    float* __restrict__ zw) {
  const int bt = blockIdx.x;
  const int b = bt / T_LEN, t = bt - b * T_LEN;
  const int j = threadIdx.x;
  __shared__ float2 Wl[1280];

  const float* zb = z + b * 256000;
  float f0 = 0.f, f1 = 0.f, c1 = 0.f, c2 = 0.f;
  {
    int zi0 = t * 256 + j - 255;
    if (zi0 >= 0) f0 = zb[zi0];
    int zi1 = t * 256 + j + 1;
    if (zi1 < 256000) f1 = zb[zi1];
    if (j >= 145) { int m = j - 145; c1 = P0[bt * 224 + m] + P1[bt * 224 + m]; }
    if (j < 111)  { int m = j + 111; c2 = P0[bt * 224 + m] + P1[bt * 224 + m]; }
  }
  {
    float sw, cw;
    __sincosf(STEP * (float)j, &sw, &cw);
    const float2 w1 = make_float2(cw, -sw);
    const float2 w2 = cmul(w1, w1);
    const float2 w3 = cmul(w2, w1);
    float2 t0 = make_float2(c2, f0);
    float2 t1 = make_float2(-c2, f0);
    float2 t2 = make_float2(c1, f1);
    float2 t3 = make_float2(f1, -c1);
    Wl[LIDX(j)]       = cadd(t0, t2);
    Wl[LIDX(j + 256)] = cmul(cadd(t1, t3), w1);
    Wl[LIDX(j + 512)] = cmul(csub(t0, t2), w2);
    Wl[LIDX(j + 768)] = cmul(csub(t1, t3), w3);
  }
  __syncthreads();

  fwd_stage<256>(Wl, j);  __syncthreads();
  fwd_stage<64>(Wl, j);   __syncthreads();
  fwd_stage<16>(Wl, j);   __syncthreads();

  const int base = 4 * j;
  float2 X[4];
  {
    float2 u0 = Wl[LIDX(base)], u1 = Wl[LIDX(base + 1)];
    float2 u2 = Wl[LIDX(base + 2)], u3 = Wl[LIDX(base + 3)];
    float2 t0 = cadd(u0, u2), t1 = csub(u0, u2), t2 = cadd(u1, u3), bd = csub(u1, u3);
    float2 t3 = make_float2(bd.y, -bd.x);
    X[0] = cadd(t0, t2); X[1] = cadd(t1, t3); X[2] = csub(t0, t2); X[3] = csub(t1, t3);
  }
#pragma unroll
  for (int q = 0; q < 4; ++q) Wl[LIDX(base + q)] = X[q];
  __syncthreads();

  const int r0 = rev4d(j);
  const bool self0 = (r0 == 0);
  const int jp = self0 ? 0 : rev4d((256 - r0) & 255);
  float2 P[4];
#pragma unroll
  for (int q = 0; q < 4; ++q) P[q] = Wl[LIDX(4 * jp + q)];
  float2 S[4];
#pragma unroll
  for (int q = 0; q < 4; ++q) {
    float2 A = X[q];
    float2 Bc0 = P[(4 - q) & 3];
    float2 Bc1 = P[3 - q];
    float2 Bc = self0 ? Bc0 : Bc1;
    float2 Y = make_float2(0.5f * (A.x + Bc.x), 0.5f * (A.y - Bc.y));
    float2 F = make_float2(0.5f * (A.y + Bc.y), -0.5f * (A.x - Bc.x));
    float mag = __expf(Y.x * 2.30258509299404568402f);
    float sy, cy;
    __sincosf(Y.y, &sy, &cy);
    float gr = mag * cy, gi = mag * sy;
    S[q] = make_float2(fmaf(F.x, gr, F.y * gi), fmaf(F.x, gi, -(F.y * gr)));
  }
  __syncthreads();
  {
    float2 t0 = cadd(S[0], S[2]), t1 = csub(S[0], S[2]), t2 = cadd(S[1], S[3]), bd = csub(S[1], S[3]);
    float2 t3 = make_float2(-bd.y, bd.x);
    Wl[LIDX(base)]     = cadd(t0, t2);
    Wl[LIDX(base + 1)] = cadd(t1, t3);
    Wl[LIDX(base + 2)] = csub(t0, t2);
    Wl[LIDX(base + 3)] = csub(t1, t3);
  }
  __syncthreads();

  inv_stage<16>(Wl, j);   __syncthreads();
  inv_stage<64>(Wl, j);   __syncthreads();
  inv_stage<256>(Wl, j);  __syncthreads();

  {
    float sw, cw;
    __sincosf(STEP * (float)j, &sw, &cw);
    float w2x = fmaf(cw, cw, -(sw * sw)), w2y = 2.f * cw * sw;
    float w3x = fmaf(w2x, cw, -(w2y * sw)), w3y = fmaf(w2x, sw, w2y * cw);
    float2 A = Wl[LIDX(j)];
    float2 B = Wl[LIDX(j + 256)];
    float2 C2 = Wl[LIDX(j + 512)];
    float2 D = Wl[LIDX(j + 768)];
    float bx = fmaf(B.x, cw, -(B.y * sw)), by = fmaf(B.x, sw, B.y * cw);
    float cx = fmaf(C2.x, w2x, -(C2.y * w2y));
    float dx = fmaf(D.x, w3x, -(D.y * w3y)), dy = fmaf(D.x, w3y, D.y * w3x);
    float cj    = (A.x + cx) + (bx + dx);
    float cj256 = (A.x - cx) - (by - dy);
    const float ISC = 1.0f / 1024.0f;
    int n1 = 511 - j, n2 = 255 - j;
    float wn1 = 0.5f - 0.5f * __cosf(STEP * 2.f * (float)n1);
    float wn2 = 0.5f - 0.5f * __cosf(STEP * 2.f * (float)n2);
    zw[bt * 512 + n1] = cj * ISC * wn1;
    zw[bt * 512 + n2] = cj256 * ISC * wn2;
  }
}

// ---- overlap-add --------------------------------------------------------------
__global__ __launch_bounds__(256) void k_ola(const float* __restrict__ zw,
                                             float* __restrict__ out) {
  int idx = blockIdx.x * 256 + threadIdx.x;
  int j = idx & 255;
  int bt = idx >> 8;
  int t = bt % T_LEN;
  int btm = (t == 0) ? bt + (T_LEN - 1) : bt - 1;
  out[idx] = zw[bt * 512 + j] + zw[btm * 512 + 256 + j];
}

extern "C" void kernel_launch(void* const* d_in, const int* in_sizes, int n_in,
                              void* d_out, int out_size, void* d_ws, size_t ws_size,
                              hipStream_t stream) {
  const float* x  = (const float*)d_in[0];
  const float* z  = (const float*)d_in[1];
  const float* W1 = (const float*)d_in[2];
  const float* b1 = (const float*)d_in[3];
  const float* W2 = (const float*)d_in[4];
  const float* b2 = (const float*)d_in[5];
  const float* W3 = (const float*)d_in[6];
  const float* b3 = (const float*)d_in[7];
  const float* W4 = (const float*)d_in[8];
  const float* b4 = (const float*)d_in[9];

  float* ws   = (float*)d_ws;
  float* bufA = ws;                     // 2,048,000 (h1)
  float* bufC = ws + 2048000;           // 2,048,000 (h2)
  __hip_bfloat16* h3bf = (__hip_bfloat16*)(ws + 4096000);  // 1,024,000 f32 slots
  float* P0   = ws + 5120000;           // 1,792,000
  float* zwB  = ws + 8704000;           // 4,096,000
  float* Wt1  = ws + 12800000;          //    61,440
  float* Wt2  = ws + 12861440;          //    24,576
  float* Wt3  = ws + 12886016;          //    24,576
  __hip_bfloat16* Wc = (__hip_bfloat16*)(ws + 12910592);   // 98,304 f32 slots
  float* P1   = P0 + 1792000;

  dim3 blk(256);
  k_tw1<<<240, blk, 0, stream>>>(W1, Wt1);
  k_tw2<<<96,  blk, 0, stream>>>(W2, Wt2);
  k_tw2<<<96,  blk, 0, stream>>>(W3, Wt3);
  k_tw4c<<<768, blk, 0, stream>>>(W4, Wc);

  dim3 cgrid10(T_LEN / 10, B_N);   // (100, 8)
  k_conv1t<<<cgrid10, blk, 0, stream>>>(x, Wt1, b1, bufA);
  k_convgt<<<cgrid10, blk, 0, stream>>>(bufA, Wt2, b2, bufC);
  k_convgt_b<<<cgrid10, blk, 0, stream>>>(bufC, Wt3, b3, h3bf);
  dim3 g4(16, B_N, 2);
  k_conv4m<<<g4, blk, 0, stream>>>(h3bf, Wc, b4, P0);
  k_fft<<<B_N * T_LEN, blk, 0, stream>>>(P0, P1, z, zwB);
  k_ola<<<B_N * T_LEN, blk, 0, stream>>>(zwB, (float*)d_out);
}

// Round 8
// 179.510 us; speedup vs baseline: 4.1091x; 1.0328x over previous
//
#include <hip/hip_runtime.h>
#include <hip/hip_bf16.h>

#define T_LEN 1000
#define B_N 8
#define IN_CH 80
#define CONV_CH 256
#define CCEP_N 222

typedef short s8v __attribute__((ext_vector_type(8)));    // 8 bf16 (4 VGPRs)
typedef float f16v __attribute__((ext_vector_type(16)));  // MFMA 32x32 acc

#define TWO_PI 6.28318530717958647692f

// ===================== fused prep kernel (weights + tables) ===================
// blocks [0,240): W1 transpose; [240,336): W2; [336,432): W3; [432,1200): W4
// chunked bf16; [1200,1206): twiddle table (1020 float2) + window table (512).
// twTab layout per stage block (Q): OFF + r*Q + pos = (cos,sin)(2pi*(r+1)*pos/(4Q))
//   Q=256 OFF 0 (768) | Q=64 OFF 768 (192) | Q=16 OFF 960 (48) | Q=4 OFF 1008 (12)
__global__ __launch_bounds__(256) void k_prep(
    const float* __restrict__ W1, const float* __restrict__ W2,
    const float* __restrict__ W3, const float* __restrict__ W4,
    float* __restrict__ Wt1, float* __restrict__ Wt2, float* __restrict__ Wt3,
    __hip_bfloat16* __restrict__ Wc, float2* __restrict__ twTab,
    float* __restrict__ winTab) {
  const int bid = blockIdx.x, tid = threadIdx.x;
  if (bid < 240) {
    int e = bid * 256 + tid;                 // 61440
    int o = e / 240, k = e - o * 240;
    Wt1[k * 256 + o] = W1[e];
  } else if (bid < 336) {
    int e = (bid - 240) * 256 + tid;         // 24576
    int o = e / 96, k = e - o * 96;
    Wt2[k * 256 + o] = W2[e];
  } else if (bid < 432) {
    int e = (bid - 336) * 256 + tid;
    int o = e / 96, k = e - o * 96;
    Wt3[k * 256 + o] = W3[e];
  } else if (bid < 1200) {
    int e = (bid - 432) * 256 + tid;         // 196608
    int kloc = e & 31, n = (e >> 5) & 255, chg = e >> 13;
    int kp = chg * 32 + kloc;
    int kappa = kp >> 8, i = kp & 255;
    float v = 0.f;
    if (n < CCEP_N) {
      float invq = 1.f / (float)((n < 111) ? (111 - n) : (n - 110));
      v = W4[n * 768 + i * 3 + kappa] * invq;
    }
    Wc[e] = __float2bfloat16(v);
  } else {
    int e = (bid - 1200) * 256 + tid;        // 0..1535
    if (e < 1020) {
      int Q, off;
      if (e < 768)       { Q = 256; off = 0; }
      else if (e < 960)  { Q = 64;  off = 768; }
      else if (e < 1008) { Q = 16;  off = 960; }
      else               { Q = 4;   off = 1008; }
      int rem = e - off;
      int r = rem / Q, pos = rem - r * Q;
      float ang = (TWO_PI * (float)((r + 1) * pos)) / (float)(4 * Q);
      float s, c;
      sincosf(ang, &s, &c);
      twTab[e] = make_float2(c, s);
    } else if (e < 1532) {
      int n = e - 1020;
      winTab[n] = (0.5f - 0.5f * cosf(TWO_PI * (float)n / 512.f)) * (1.f / 1024.f);
    }
  }
}

// ---------------- conv1: (B,T,80) -> (B,T,256), k=3 same, relu ----------------
__global__ __launch_bounds__(256) void k_conv1t(const float* __restrict__ x,
    const float* __restrict__ Wt, const float* __restrict__ bias,
    float* __restrict__ out) {
  const int b = blockIdx.y;
  const int t0 = blockIdx.x * 10;
  const int o = threadIdx.x;
  __shared__ float hs[IN_CH * 14];
  for (int e = threadIdx.x; e < 12 * IN_CH; e += 256) {
    int r = e / IN_CH, c = e - r * IN_CH;
    int t = t0 - 1 + r;
    hs[c * 14 + r] = (t >= 0 && t < T_LEN) ? x[(b * T_LEN + t) * IN_CH + c] : 0.f;
  }
  __syncthreads();
  float acc[10];
  float bv = bias[o];
#pragma unroll
  for (int j = 0; j < 10; j++) acc[j] = bv;
  for (int i = 0; i < IN_CH; i++) {
    float w0 = Wt[(3 * i + 0) * 256 + o];
    float w1 = Wt[(3 * i + 1) * 256 + o];
    float w2 = Wt[(3 * i + 2) * 256 + o];
    const float* row = &hs[i * 14];
    float a[12];
#pragma unroll
    for (int u = 0; u < 6; u++) *(float2*)&a[2 * u] = *(const float2*)(row + 2 * u);
#pragma unroll
    for (int j = 0; j < 10; j++) {
      acc[j] = fmaf(a[j], w0, acc[j]);
      acc[j] = fmaf(a[j + 1], w1, acc[j]);
      acc[j] = fmaf(a[j + 2], w2, acc[j]);
    }
  }
#pragma unroll
  for (int j = 0; j < 10; j++)
    out[(b * T_LEN + t0 + j) * CONV_CH + o] = fmaxf(acc[j], 0.f);
}

// ------------- grouped conv: (B,T,256)->(B,T,256), groups=8, relu -------------
__global__ __launch_bounds__(256) void k_convgt(const float* __restrict__ h,
    const float* __restrict__ Wt, const float* __restrict__ bias,
    float* __restrict__ out) {
  const int b = blockIdx.y;
  const int t0 = blockIdx.x * 10;
  const int o = threadIdx.x;
  const int cb = (o >> 5) << 5;
  __shared__ float hs[CONV_CH * 14];
  for (int e = threadIdx.x; e < 12 * CONV_CH; e += 256) {
    int r = e >> 8, c = e & 255;
    int t = t0 - 1 + r;
    hs[c * 14 + r] = (t >= 0 && t < T_LEN) ? h[(b * T_LEN + t) * CONV_CH + c] : 0.f;
  }
  __syncthreads();
  float acc[10];
  float bv = bias[o];
#pragma unroll
  for (int j = 0; j < 10; j++) acc[j] = bv;
  for (int i = 0; i < 32; i++) {
    float w0 = Wt[(3 * i + 0) * 256 + o];
    float w1 = Wt[(3 * i + 1) * 256 + o];
    float w2 = Wt[(3 * i + 2) * 256 + o];
    const float* row = &hs[(cb + i) * 14];
    float a[12];
#pragma unroll
    for (int u = 0; u < 6; u++) *(float2*)&a[2 * u] = *(const float2*)(row + 2 * u);
#pragma unroll
    for (int j = 0; j < 10; j++) {
      acc[j] = fmaf(a[j], w0, acc[j]);
      acc[j] = fmaf(a[j + 1], w1, acc[j]);
      acc[j] = fmaf(a[j + 2], w2, acc[j]);
    }
  }
#pragma unroll
  for (int j = 0; j < 10; j++)
    out[(b * T_LEN + t0 + j) * CONV_CH + o] = fmaxf(acc[j], 0.f);
}

// ------------- grouped conv variant writing bf16 (h3 feeds MFMA conv4) --------
__global__ __launch_bounds__(256) void k_convgt_b(const float* __restrict__ h,
    const float* __restrict__ Wt, const float* __restrict__ bias,
    __hip_bfloat16* __restrict__ out) {
  const int b = blockIdx.y;
  const int t0 = blockIdx.x * 10;
  const int o = threadIdx.x;
  const int cb = (o >> 5) << 5;
  __shared__ float hs[CONV_CH * 14];
  for (int e = threadIdx.x; e < 12 * CONV_CH; e += 256) {
    int r = e >> 8, c = e & 255;
    int t = t0 - 1 + r;
    hs[c * 14 + r] = (t >= 0 && t < T_LEN) ? h[(b * T_LEN + t) * CONV_CH + c] : 0.f;
  }
  __syncthreads();
  float acc[10];
  float bv = bias[o];
#pragma unroll
  for (int j = 0; j < 10; j++) acc[j] = bv;
  for (int i = 0; i < 32; i++) {
    float w0 = Wt[(3 * i + 0) * 256 + o];
    float w1 = Wt[(3 * i + 1) * 256 + o];
    float w2 = Wt[(3 * i + 2) * 256 + o];
    const float* row = &hs[(cb + i) * 14];
    float a[12];
#pragma unroll
    for (int u = 0; u < 6; u++) *(float2*)&a[2 * u] = *(const float2*)(row + 2 * u);
#pragma unroll
    for (int j = 0; j < 10; j++) {
      acc[j] = fmaf(a[j], w0, acc[j]);
      acc[j] = fmaf(a[j + 1], w1, acc[j]);
      acc[j] = fmaf(a[j + 2], w2, acc[j]);
    }
  }
#pragma unroll
  for (int j = 0; j < 10; j++)
    out[(b * T_LEN + t0 + j) * CONV_CH + o] = __float2bfloat16(fmaxf(acc[j], 0.f));
}

// ============ conv4 as MFMA GEMM, K-split x4: 512 blocks (2/CU) ===============
#define APITCH 264
#define BPITCH 40
#define PSTRIDE 1792000
__global__ __launch_bounds__(256) void k_conv4m(
    const __hip_bfloat16* __restrict__ h3, const __hip_bfloat16* __restrict__ Wc,
    const float* __restrict__ bias, float* __restrict__ Pbase) {
  const int mb = blockIdx.x, b = blockIdx.y, ks = blockIdx.z;
  float* __restrict__ P = Pbase + (size_t)ks * PSTRIDE;
  const int t0 = mb * 64;
  const int tid = threadIdx.x;
  const int w = tid >> 6, lane = tid & 63;
  const int wm = w >> 1, wn = w & 1;
  const int lm = lane & 31, half = lane >> 5;

  __shared__ short h3s[67 * APITCH];
  __shared__ short Bs[2][256 * BPITCH];

  const ushort* h3u = (const ushort*)h3;
  for (int g = tid; g < 67 * 64; g += 256) {
    int rr = g >> 6, c4 = g & 63;
    int t = t0 + rr - 1;
    uint2 v = make_uint2(0u, 0u);
    if (t >= 0 && t < T_LEN)
      v = *(const uint2*)(h3u + (b * T_LEN + t) * CONV_CH + c4 * 4);
    *(uint2*)(h3s + rr * APITCH + c4 * 4) = v;
  }

  const ushort* Wu = (const ushort*)(Wc) + (size_t)(ks * 6) * 8192;
#pragma unroll
  for (int it = 0; it < 4; ++it) {
    int idx = (it * 256 + tid) * 8;
    uint4 v = *(const uint4*)(Wu + idx);
    int n = idx >> 5, kloc = idx & 31;
    *(uint4*)(Bs[0] + n * BPITCH + kloc) = v;
  }
  __syncthreads();

  f16v acc0 = {}, acc1 = {}, acc2 = {}, acc3 = {};

  for (int ch = 0; ch < 6; ++ch) {
    const int p = ch & 1;
    if (ch < 5) {
      const ushort* src = Wu + (ch + 1) * 8192;
#pragma unroll
      for (int it = 0; it < 4; ++it) {
        int idx = (it * 256 + tid) * 8;
        uint4 v = *(const uint4*)(src + idx);
        int n = idx >> 5, kloc = idx & 31;
        *(uint4*)(Bs[p ^ 1] + n * BPITCH + kloc) = v;
      }
    }
#pragma unroll
    for (int s = 0; s < 2; ++s) {
      int k0 = ks * 192 + ch * 32 + s * 16;
      int kappa = k0 >> 8, i0 = k0 & 255;
      s8v a = *(const s8v*)(h3s + (wm * 32 + lm + kappa) * APITCH + i0 + half * 8);
      const short* bp = Bs[p] + (wn * 128 + lm) * BPITCH + s * 16 + half * 8;
      s8v b0 = *(const s8v*)(bp);
      s8v b1 = *(const s8v*)(bp + 32 * BPITCH);
      s8v b2 = *(const s8v*)(bp + 64 * BPITCH);
      s8v b3 = *(const s8v*)(bp + 96 * BPITCH);
      acc0 = __builtin_amdgcn_mfma_f32_32x32x16_bf16(a, b0, acc0, 0, 0, 0);
      acc1 = __builtin_amdgcn_mfma_f32_32x32x16_bf16(a, b1, acc1, 0, 0, 0);
      acc2 = __builtin_amdgcn_mfma_f32_32x32x16_bf16(a, b2, acc2, 0, 0, 0);
      acc3 = __builtin_amdgcn_mfma_f32_32x32x16_bf16(a, b3, acc3, 0, 0, 0);
    }
    __syncthreads();
  }

  const int col = lm;
#pragma unroll
  for (int nt = 0; nt < 4; ++nt) {
    int c = wn * 128 + nt * 32 + col;
    if (c >= CCEP_N) continue;
    float bq = 0.f;
    if (ks == 0) {
      float invq = 1.f / (float)((c < 111) ? (111 - c) : (c - 110));
      bq = bias[c] * invq;
    }
    const f16v* A = (nt == 0) ? &acc0 : (nt == 1) ? &acc1 : (nt == 2) ? &acc2 : &acc3;
#pragma unroll
    for (int reg = 0; reg < 16; ++reg) {
      int row = (reg & 3) + 8 * (reg >> 2) + 4 * half;
      int t = t0 + wm * 32 + row;
      if (t < T_LEN)
        P[(size_t)(b * T_LEN + t) * 224 + c] = (*A)[reg] + bq;
    }
  }
}

// ============================ fused FFT kernel ================================
__device__ __forceinline__ float2 cmul(float2 a, float2 b) {
  return make_float2(fmaf(a.x, b.x, -(a.y * b.y)), fmaf(a.x, b.y, a.y * b.x));
}
__device__ __forceinline__ float2 cadd(float2 a, float2 b) { return make_float2(a.x + b.x, a.y + b.y); }
__device__ __forceinline__ float2 csub(float2 a, float2 b) { return make_float2(a.x - b.x, a.y - b.y); }

#define LIDX(i) ((i) + ((i) >> 2))

// Q = M/4, OFF = table offset for this stage
template <int Q, int OFF>
__device__ __forceinline__ void fwd_stage_t(float2* __restrict__ X,
    const float2* __restrict__ Tw, int j) {
  const int pos = j & (Q - 1);
  const int base = ((j - pos) << 2) + pos;
  float2 e1 = Tw[OFF + pos], e2 = Tw[OFF + Q + pos], e3 = Tw[OFF + 2 * Q + pos];
  const float2 w1 = make_float2(e1.x, -e1.y);
  const float2 w2 = make_float2(e2.x, -e2.y);
  const float2 w3 = make_float2(e3.x, -e3.y);
  float2 a = X[LIDX(base)], b = X[LIDX(base + Q)];
  float2 cc = X[LIDX(base + 2 * Q)], d = X[LIDX(base + 3 * Q)];
  float2 t0 = cadd(a, cc), t1 = csub(a, cc), t2 = cadd(b, d), bd = csub(b, d);
  float2 t3 = make_float2(bd.y, -bd.x);
  X[LIDX(base)]         = cadd(t0, t2);
  X[LIDX(base + Q)]     = cmul(cadd(t1, t3), w1);
  X[LIDX(base + 2 * Q)] = cmul(csub(t0, t2), w2);
  X[LIDX(base + 3 * Q)] = cmul(csub(t1, t3), w3);
}

template <int Q, int OFF>
__device__ __forceinline__ void inv_stage_t(float2* __restrict__ X,
    const float2* __restrict__ Tw, int j) {
  const int pos = j & (Q - 1);
  const int base = ((j - pos) << 2) + pos;
  const float2 w1 = Tw[OFF + pos];
  const float2 w2 = Tw[OFF + Q + pos];
  const float2 w3 = Tw[OFF + 2 * Q + pos];
  float2 a = X[LIDX(base)];
  float2 b = cmul(X[LIDX(base + Q)], w1);
  float2 cc = cmul(X[LIDX(base + 2 * Q)], w2);
  float2 d = cmul(X[LIDX(base + 3 * Q)], w3);
  float2 t0 = cadd(a, cc), t1 = csub(a, cc), t2 = cadd(b, d), bd = csub(b, d);
  float2 t3 = make_float2(-bd.y, bd.x);
  X[LIDX(base)]         = cadd(t0, t2);
  X[LIDX(base + Q)]     = cadd(t1, t3);
  X[LIDX(base + 2 * Q)] = csub(t0, t2);
  X[LIDX(base + 3 * Q)] = csub(t1, t3);
}

__device__ __forceinline__ int rev4d(int v) {
  return ((v & 3) << 6) | (((v >> 2) & 3) << 4) | (((v >> 4) & 3) << 2) | ((v >> 6) & 3);
}

// grid (1000, 8). Writes out directly via two atomicAdds (out pre-zeroed):
// thread j: l-part -> out[b, t*256 + (255-j)], r-part -> out[b, ((t+1)%T)*256 + (255-j)].
__global__ __launch_bounds__(256) void k_fft(const float* __restrict__ Pb,
    const float* __restrict__ z, const float2* __restrict__ twg,
    const float* __restrict__ wing, float* __restrict__ out) {
  const int t = blockIdx.x, b = blockIdx.y;
  const int bt = b * T_LEN + t;
  const int j = threadIdx.x;
  __shared__ float2 Wl[1280];
  __shared__ float2 Tws[1020];
  for (int e = j; e < 1020; e += 256) Tws[e] = twg[e];

  const float* zb = z + b * 256000;
  float f0 = 0.f, f1 = 0.f, c1 = 0.f, c2 = 0.f;
  {
    int zi0 = t * 256 + j - 255;
    if (zi0 >= 0) f0 = zb[zi0];
    int zi1 = t * 256 + j + 1;
    if (zi1 < 256000) f1 = zb[zi1];
    if (j >= 145) {
      int m = bt * 224 + (j - 145);
      c1 = (Pb[m] + Pb[m + PSTRIDE]) + (Pb[m + 2 * PSTRIDE] + Pb[m + 3 * PSTRIDE]);
    }
    if (j < 111) {
      int m = bt * 224 + (j + 111);
      c2 = (Pb[m] + Pb[m + PSTRIDE]) + (Pb[m + 2 * PSTRIDE] + Pb[m + 3 * PSTRIDE]);
    }
  }
  __syncthreads();   // Tws ready

  // ---- first fwd stage (M=1024, Q=256, pos=j), sparse inputs ----
  {
    float2 e1 = Tws[j], e2 = Tws[256 + j], e3 = Tws[512 + j];
    const float2 w1 = make_float2(e1.x, -e1.y);
    const float2 w2 = make_float2(e2.x, -e2.y);
    const float2 w3 = make_float2(e3.x, -e3.y);
    float2 t0 = make_float2(c2, f0);          // x0+x2
    float2 t1 = make_float2(-c2, f0);         // x0-x2
    float2 t2 = make_float2(c1, f1);          // x1+x3
    float2 t3 = make_float2(f1, -c1);         // -i*(x1-x3)
    Wl[LIDX(j)]       = cadd(t0, t2);
    Wl[LIDX(j + 256)] = cmul(cadd(t1, t3), w1);
    Wl[LIDX(j + 512)] = cmul(csub(t0, t2), w2);
    Wl[LIDX(j + 768)] = cmul(csub(t1, t3), w3);
  }
  __syncthreads();

  fwd_stage_t<64, 768>(Wl, Tws, j);  __syncthreads();   // M=256
  fwd_stage_t<16, 960>(Wl, Tws, j);  __syncthreads();   // M=64
  fwd_stage_t<4, 1008>(Wl, Tws, j);  __syncthreads();   // M=16

  const int base = 4 * j;
  float2 X[4];
  {
    float2 u0 = Wl[LIDX(base)], u1 = Wl[LIDX(base + 1)];
    float2 u2 = Wl[LIDX(base + 2)], u3 = Wl[LIDX(base + 3)];
    float2 t0 = cadd(u0, u2), t1 = csub(u0, u2), t2 = cadd(u1, u3), bd = csub(u1, u3);
    float2 t3 = make_float2(bd.y, -bd.x);
    X[0] = cadd(t0, t2); X[1] = cadd(t1, t3); X[2] = csub(t0, t2); X[3] = csub(t1, t3);
  }
#pragma unroll
  for (int q = 0; q < 4; ++q) Wl[LIDX(base + q)] = X[q];
  __syncthreads();

  const int r0 = rev4d(j);
  const bool self0 = (r0 == 0);
  const int jp = self0 ? 0 : rev4d((256 - r0) & 255);
  float2 P[4];
#pragma unroll
  for (int q = 0; q < 4; ++q) P[q] = Wl[LIDX(4 * jp + q)];
  float2 S[4];
#pragma unroll
  for (int q = 0; q < 4; ++q) {
    float2 A = X[q];
    float2 Bc0 = P[(4 - q) & 3];
    float2 Bc1 = P[3 - q];
    float2 Bc = self0 ? Bc0 : Bc1;
    float2 Y = make_float2(0.5f * (A.x + Bc.x), 0.5f * (A.y - Bc.y));
    float2 F = make_float2(0.5f * (A.y + Bc.y), -0.5f * (A.x - Bc.x));
    float mag = __expf(Y.x * 2.30258509299404568402f);
    float sy, cy;
    __sincosf(Y.y, &sy, &cy);
    float gr = mag * cy, gi = mag * sy;
    S[q] = make_float2(fmaf(F.x, gr, F.y * gi), fmaf(F.x, gi, -(F.y * gr)));
  }
  __syncthreads();
  {
    float2 t0 = cadd(S[0], S[2]), t1 = csub(S[0], S[2]), t2 = cadd(S[1], S[3]), bd = csub(S[1], S[3]);
    float2 t3 = make_float2(-bd.y, bd.x);
    Wl[LIDX(base)]     = cadd(t0, t2);
    Wl[LIDX(base + 1)] = cadd(t1, t3);
    Wl[LIDX(base + 2)] = csub(t0, t2);
    Wl[LIDX(base + 3)] = csub(t1, t3);
  }
  __syncthreads();

  inv_stage_t<4, 1008>(Wl, Tws, j);  __syncthreads();   // M=16
  inv_stage_t<16, 960>(Wl, Tws, j);  __syncthreads();   // M=64
  inv_stage_t<64, 768>(Wl, Tws, j);  __syncthreads();   // M=256

  // ---- final inverse stage (M=1024) inlined: Re(C[j]), Re(C[j+256]) ----
  {
    float2 w1 = Tws[j], w2 = Tws[256 + j], w3 = Tws[512 + j];
    float2 A = Wl[LIDX(j)];
    float2 B = Wl[LIDX(j + 256)];
    float2 C2 = Wl[LIDX(j + 512)];
    float2 D = Wl[LIDX(j + 768)];
    float bx = fmaf(B.x, w1.x, -(B.y * w1.y)), by = fmaf(B.x, w1.y, B.y * w1.x);
    float cx = fmaf(C2.x, w2.x, -(C2.y * w2.y));
    float dx = fmaf(D.x, w3.x, -(D.y * w3.y)), dy = fmaf(D.x, w3.y, D.y * w3.x);
    float cj    = (A.x + cx) + (bx + dx);          // Re(C[j])      -> n1 = 511-j (r-part)
    float cj256 = (A.x - cx) - (by - dy);          // Re(C[j+256])  -> n2 = 255-j (l-part)
    int n1 = 511 - j, n2 = 255 - j;
    float wn1 = wing[n1], wn2 = wing[n2];          // window/1024 folded
    int tp = (t + 1 == T_LEN) ? 0 : t + 1;
    atomicAdd(&out[b * 256000 + t * 256 + n2], cj256 * wn2);
    atomicAdd(&out[b * 256000 + tp * 256 + n2], cj * wn1);
  }
}

extern "C" void kernel_launch(void* const* d_in, const int* in_sizes, int n_in,
                              void* d_out, int out_size, void* d_ws, size_t ws_size,
                              hipStream_t stream) {
  const float* x  = (const float*)d_in[0];
  const float* z  = (const float*)d_in[1];
  const float* W1 = (const float*)d_in[2];
  const float* b1 = (const float*)d_in[3];
  const float* W2 = (const float*)d_in[4];
  const float* b2 = (const float*)d_in[5];
  const float* W3 = (const float*)d_in[6];
  const float* b3 = (const float*)d_in[7];
  const float* W4 = (const float*)d_in[8];
  const float* b4 = (const float*)d_in[9];

  float* ws   = (float*)d_ws;
  float* bufA = ws;                      // 2,048,000 (h1)
  float* bufC = ws + 2048000;            // 2,048,000 (h2)
  __hip_bfloat16* h3bf = (__hip_bfloat16*)(ws + 4096000);  // 1,024,000 f32 slots
  float* Pb   = ws + 5120000;            // 4 x 1,792,000 = 7,168,000
  float* Wt1  = ws + 12288000;           //    61,440
  float* Wt2  = ws + 12349440;           //    24,576
  float* Wt3  = ws + 12374016;           //    24,576
  __hip_bfloat16* Wc = (__hip_bfloat16*)(ws + 12398592);   // 98,304 f32 slots
  float2* twTab = (float2*)(ws + 12496896);                // 1020 float2
  float* winTab = ws + 12498944;                           // 512
  // end 12,499,456 f32 = 50 MB

  float* out = (float*)d_out;
  hipMemsetAsync(out, 0, (size_t)2048000 * sizeof(float), stream);

  dim3 blk(256);
  k_prep<<<1206, blk, 0, stream>>>(W1, W2, W3, W4, Wt1, Wt2, Wt3, Wc, twTab, winTab);

  dim3 cgrid10(T_LEN / 10, B_N);   // (100, 8)
  k_conv1t<<<cgrid10, blk, 0, stream>>>(x, Wt1, b1, bufA);
  k_convgt<<<cgrid10, blk, 0, stream>>>(bufA, Wt2, b2, bufC);
  k_convgt_b<<<cgrid10, blk, 0, stream>>>(bufC, Wt3, b3, h3bf);
  dim3 g4(16, B_N, 4);
  k_conv4m<<<g4, blk, 0, stream>>>(h3bf, Wc, b4, Pb);
  dim3 gf(T_LEN, B_N);
  k_fft<<<gf, blk, 0, stream>>>(Pb, z, twTab, winTab, out);
}

// Round 10
// 172.559 us; speedup vs baseline: 4.2746x; 1.0403x over previous
//
#include <hip/hip_runtime.h>
#include <hip/hip_bf16.h>

#define T_LEN 1000
#define B_N 8
#define IN_CH 80
#define CONV_CH 256
#define CCEP_N 222

typedef short s8v __attribute__((ext_vector_type(8)));    // 8 bf16 (4 VGPRs)
typedef float f16v __attribute__((ext_vector_type(16)));  // MFMA 32x32 acc

#define TWO_PI 6.28318530717958647692f

// ===================== fused prep kernel (weights + tables + out-zero) ========
// blocks [0,240): W1^T; [240,336): W2^T; [336,432): W3^T; [432,1200): W4 chunks;
// [1200,1206): twiddle (1020 float2) + window (512); [1206,2206): zero d_out.
__global__ __launch_bounds__(256) void k_prep(
    const float* __restrict__ W1, const float* __restrict__ W2,
    const float* __restrict__ W3, const float* __restrict__ W4,
    float* __restrict__ Wt1, float* __restrict__ Wt2, float* __restrict__ Wt3,
    __hip_bfloat16* __restrict__ Wc, float2* __restrict__ twTab,
    float* __restrict__ winTab, float* __restrict__ out) {
  const int bid = blockIdx.x, tid = threadIdx.x;
  if (bid < 240) {
    int e = bid * 256 + tid;                 // 61440
    int o = e / 240, k = e - o * 240;
    Wt1[k * 256 + o] = W1[e];
  } else if (bid < 336) {
    int e = (bid - 240) * 256 + tid;         // 24576
    int o = e / 96, k = e - o * 96;
    Wt2[k * 256 + o] = W2[e];
  } else if (bid < 432) {
    int e = (bid - 336) * 256 + tid;
    int o = e / 96, k = e - o * 96;
    Wt3[k * 256 + o] = W3[e];
  } else if (bid < 1200) {
    int e = (bid - 432) * 256 + tid;         // 196608
    int kloc = e & 31, n = (e >> 5) & 255, chg = e >> 13;
    int kp = chg * 32 + kloc;
    int kappa = kp >> 8, i = kp & 255;
    float v = 0.f;
    if (n < CCEP_N) {
      float invq = 1.f / (float)((n < 111) ? (111 - n) : (n - 110));
      v = W4[n * 768 + i * 3 + kappa] * invq;
    }
    Wc[e] = __float2bfloat16(v);
  } else if (bid < 1206) {
    int e = (bid - 1200) * 256 + tid;        // 0..1535
    if (e < 1020) {
      int Q, off;
      if (e < 768)       { Q = 256; off = 0; }
      else if (e < 960)  { Q = 64;  off = 768; }
      else if (e < 1008) { Q = 16;  off = 960; }
      else               { Q = 4;   off = 1008; }
      int rem = e - off;
      int r = rem / Q, pos = rem - r * Q;
      float ang = (TWO_PI * (float)((r + 1) * pos)) / (float)(4 * Q);
      float s, c;
      sincosf(ang, &s, &c);
      twTab[e] = make_float2(c, s);
    } else if (e < 1532) {
      int n = e - 1020;
      winTab[n] = (0.5f - 0.5f * cosf(TWO_PI * (float)n / 512.f)) * (1.f / 1024.f);
    }
  } else {
    // zero out: 1000 blocks x 256 thr x 8 floats = 2,048,000
    int e = ((bid - 1206) * 256 + tid) * 8;
    float4 zz = make_float4(0.f, 0.f, 0.f, 0.f);
    *(float4*)(out + e) = zz;
    *(float4*)(out + e + 4) = zz;
  }
}

// ---------------- conv1: (B,T,80) -> (B,T,256), k=3 same, relu ----------------
__global__ __launch_bounds__(256) void k_conv1t(const float* __restrict__ x,
    const float* __restrict__ Wt, const float* __restrict__ bias,
    float* __restrict__ out) {
  const int b = blockIdx.y;
  const int t0 = blockIdx.x * 10;
  const int o = threadIdx.x;
  __shared__ float hs[IN_CH * 14];
  for (int e = threadIdx.x; e < 12 * IN_CH; e += 256) {
    int r = e / IN_CH, c = e - r * IN_CH;
    int t = t0 - 1 + r;
    hs[c * 14 + r] = (t >= 0 && t < T_LEN) ? x[(b * T_LEN + t) * IN_CH + c] : 0.f;
  }
  __syncthreads();
  float acc[10];
  float bv = bias[o];
#pragma unroll
  for (int j = 0; j < 10; j++) acc[j] = bv;
  for (int i = 0; i < IN_CH; i++) {
    float w0 = Wt[(3 * i + 0) * 256 + o];
    float w1 = Wt[(3 * i + 1) * 256 + o];
    float w2 = Wt[(3 * i + 2) * 256 + o];
    const float* row = &hs[i * 14];
    float a[12];
#pragma unroll
    for (int u = 0; u < 6; u++) *(float2*)&a[2 * u] = *(const float2*)(row + 2 * u);
#pragma unroll
    for (int j = 0; j < 10; j++) {
      acc[j] = fmaf(a[j], w0, acc[j]);
      acc[j] = fmaf(a[j + 1], w1, acc[j]);
      acc[j] = fmaf(a[j + 2], w2, acc[j]);
    }
  }
#pragma unroll
  for (int j = 0; j < 10; j++)
    out[(b * T_LEN + t0 + j) * CONV_CH + o] = fmaxf(acc[j], 0.f);
}

// ----- fused double grouped conv: h1 -> (h2 in LDS) -> h3 bf16, groups=8 ------
// TT=10; halo 2. h1 rows t0-2..t0+11 (14), h2 rows t0-1..t0+10 (12), h3 t0..t0+9.
// h2 rows with t outside [0,T_LEN) are ZEROED (reference "same" conv zero-pads
// layer-3's input; computing relu(conv(pad)) there would be wrong).
__global__ __launch_bounds__(256) void k_convg2(const float* __restrict__ h,
    const float* __restrict__ Wt2, const float* __restrict__ b2,
    const float* __restrict__ Wt3, const float* __restrict__ b3,
    __hip_bfloat16* __restrict__ out) {
  const int b = blockIdx.y;
  const int t0 = blockIdx.x * 10;
  const int o = threadIdx.x;
  const int cb = (o >> 5) << 5;
  __shared__ float hs1[CONV_CH * 14];
  __shared__ float hs2[CONV_CH * 14];
  for (int e = threadIdx.x; e < 14 * CONV_CH; e += 256) {
    int r = e >> 8, c = e & 255;
    int t = t0 - 2 + r;
    hs1[c * 14 + r] = (t >= 0 && t < T_LEN) ? h[(b * T_LEN + t) * CONV_CH + c] : 0.f;
  }
  __syncthreads();
  // layer 2: h2 rows r=0..11 (t = t0-1+r)
  {
    float acc[12];
    float bv = b2[o];
#pragma unroll
    for (int j = 0; j < 12; j++) acc[j] = bv;
    for (int i = 0; i < 32; i++) {
      float w0 = Wt2[(3 * i + 0) * 256 + o];
      float w1 = Wt2[(3 * i + 1) * 256 + o];
      float w2 = Wt2[(3 * i + 2) * 256 + o];
      const float* row = &hs1[(cb + i) * 14];
      float a[14];
#pragma unroll
      for (int u = 0; u < 7; u++) *(float2*)&a[2 * u] = *(const float2*)(row + 2 * u);
#pragma unroll
      for (int j = 0; j < 12; j++) {
        acc[j] = fmaf(a[j], w0, acc[j]);
        acc[j] = fmaf(a[j + 1], w1, acc[j]);
        acc[j] = fmaf(a[j + 2], w2, acc[j]);
      }
    }
#pragma unroll
    for (int j = 0; j < 12; j++) {
      int t = t0 - 1 + j;
      hs2[o * 14 + j] = (t >= 0 && t < T_LEN) ? fmaxf(acc[j], 0.f) : 0.f;
    }
  }
  __syncthreads();
  // layer 3: h3 rows j=0..9 (t = t0+j), h2 row index j..j+2
  {
    float acc[10];
    float bv = b3[o];
#pragma unroll
    for (int j = 0; j < 10; j++) acc[j] = bv;
    for (int i = 0; i < 32; i++) {
      float w0 = Wt3[(3 * i + 0) * 256 + o];
      float w1 = Wt3[(3 * i + 1) * 256 + o];
      float w2 = Wt3[(3 * i + 2) * 256 + o];
      const float* row = &hs2[(cb + i) * 14];
      float a[12];
#pragma unroll
      for (int u = 0; u < 6; u++) *(float2*)&a[2 * u] = *(const float2*)(row + 2 * u);
#pragma unroll
      for (int j = 0; j < 10; j++) {
        acc[j] = fmaf(a[j], w0, acc[j]);
        acc[j] = fmaf(a[j + 1], w1, acc[j]);
        acc[j] = fmaf(a[j + 2], w2, acc[j]);
      }
    }
#pragma unroll
    for (int j = 0; j < 10; j++)
      out[(b * T_LEN + t0 + j) * CONV_CH + o] = __float2bfloat16(fmaxf(acc[j], 0.f));
  }
}

// ============ conv4 as MFMA GEMM, K-split x4: 512 blocks (2/CU) ===============
#define APITCH 264
#define BPITCH 40
#define PSTRIDE 1792000
__global__ __launch_bounds__(256) void k_conv4m(
    const __hip_bfloat16* __restrict__ h3, const __hip_bfloat16* __restrict__ Wc,
    const float* __restrict__ bias, float* __restrict__ Pbase) {
  const int mb = blockIdx.x, b = blockIdx.y, ks = blockIdx.z;
  float* __restrict__ P = Pbase + (size_t)ks * PSTRIDE;
  const int t0 = mb * 64;
  const int tid = threadIdx.x;
  const int w = tid >> 6, lane = tid & 63;
  const int wm = w >> 1, wn = w & 1;
  const int lm = lane & 31, half = lane >> 5;

  __shared__ short h3s[67 * APITCH];
  __shared__ short Bs[2][256 * BPITCH];

  const ushort* h3u = (const ushort*)h3;
  for (int g = tid; g < 67 * 64; g += 256) {
    int rr = g >> 6, c4 = g & 63;
    int t = t0 + rr - 1;
    uint2 v = make_uint2(0u, 0u);
    if (t >= 0 && t < T_LEN)
      v = *(const uint2*)(h3u + (b * T_LEN + t) * CONV_CH + c4 * 4);
    *(uint2*)(h3s + rr * APITCH + c4 * 4) = v;
  }

  const ushort* Wu = (const ushort*)(Wc) + (size_t)(ks * 6) * 8192;
#pragma unroll
  for (int it = 0; it < 4; ++it) {
    int idx = (it * 256 + tid) * 8;
    uint4 v = *(const uint4*)(Wu + idx);
    int n = idx >> 5, kloc = idx & 31;
    *(uint4*)(Bs[0] + n * BPITCH + kloc) = v;
  }
  __syncthreads();

  f16v acc0 = {}, acc1 = {}, acc2 = {}, acc3 = {};

  for (int ch = 0; ch < 6; ++ch) {
    const int p = ch & 1;
    if (ch < 5) {
      const ushort* src = Wu + (ch + 1) * 8192;
#pragma unroll
      for (int it = 0; it < 4; ++it) {
        int idx = (it * 256 + tid) * 8;
        uint4 v = *(const uint4*)(src + idx);
        int n = idx >> 5, kloc = idx & 31;
        *(uint4*)(Bs[p ^ 1] + n * BPITCH + kloc) = v;
      }
    }
#pragma unroll
    for (int s = 0; s < 2; ++s) {
      int k0 = ks * 192 + ch * 32 + s * 16;
      int kappa = k0 >> 8, i0 = k0 & 255;
      s8v a = *(const s8v*)(h3s + (wm * 32 + lm + kappa) * APITCH + i0 + half * 8);
      const short* bp = Bs[p] + (wn * 128 + lm) * BPITCH + s * 16 + half * 8;
      s8v b0 = *(const s8v*)(bp);
      s8v b1 = *(const s8v*)(bp + 32 * BPITCH);
      s8v b2 = *(const s8v*)(bp + 64 * BPITCH);
      s8v b3 = *(const s8v*)(bp + 96 * BPITCH);
      acc0 = __builtin_amdgcn_mfma_f32_32x32x16_bf16(a, b0, acc0, 0, 0, 0);
      acc1 = __builtin_amdgcn_mfma_f32_32x32x16_bf16(a, b1, acc1, 0, 0, 0);
      acc2 = __builtin_amdgcn_mfma_f32_32x32x16_bf16(a, b2, acc2, 0, 0, 0);
      acc3 = __builtin_amdgcn_mfma_f32_32x32x16_bf16(a, b3, acc3, 0, 0, 0);
    }
    __syncthreads();
  }

  const int col = lm;
#pragma unroll
  for (int nt = 0; nt < 4; ++nt) {
    int c = wn * 128 + nt * 32 + col;
    if (c >= CCEP_N) continue;
    float bq = 0.f;
    if (ks == 0) {
      float invq = 1.f / (float)((c < 111) ? (111 - c) : (c - 110));
      bq = bias[c] * invq;
    }
    const f16v* A = (nt == 0) ? &acc0 : (nt == 1) ? &acc1 : (nt == 2) ? &acc2 : &acc3;
#pragma unroll
    for (int reg = 0; reg < 16; ++reg) {
      int row = (reg & 3) + 8 * (reg >> 2) + 4 * half;
      int t = t0 + wm * 32 + row;
      if (t < T_LEN)
        P[(size_t)(b * T_LEN + t) * 224 + c] = (*A)[reg] + bq;
    }
  }
}

// ============================ fused FFT kernel (2 frames/block) ===============
// Frames tA=2u, tB=2u+1. Two packed forward FFTs (c + i*fr per frame); S_A, S_B
// Hermitian -> ONE inverse: Z = S_A + i*S_B, IFFT(Z) = C_A + i*C_B (both real).
__device__ __forceinline__ float2 cmul(float2 a, float2 b) {
  return make_float2(fmaf(a.x, b.x, -(a.y * b.y)), fmaf(a.x, b.y, a.y * b.x));
}
__device__ __forceinline__ float2 cadd(float2 a, float2 b) { return make_float2(a.x + b.x, a.y + b.y); }
__device__ __forceinline__ float2 csub(float2 a, float2 b) { return make_float2(a.x - b.x, a.y - b.y); }

#define LIDX(i) ((i) + ((i) >> 2))

// forward stage on TWO arrays sharing one twiddle fetch
template <int Q, int OFF>
__device__ __forceinline__ void fwd_stage2(float2* __restrict__ A,
    float2* __restrict__ B, const float2* __restrict__ Tw, int j) {
  const int pos = j & (Q - 1);
  const int base = ((j - pos) << 2) + pos;
  float2 e1 = Tw[OFF + pos], e2 = Tw[OFF + Q + pos], e3 = Tw[OFF + 2 * Q + pos];
  const float2 w1 = make_float2(e1.x, -e1.y);
  const float2 w2 = make_float2(e2.x, -e2.y);
  const float2 w3 = make_float2(e3.x, -e3.y);
#pragma unroll
  for (int arr = 0; arr < 2; ++arr) {
    float2* X = arr ? B : A;
    float2 a = X[LIDX(base)], b = X[LIDX(base + Q)];
    float2 cc = X[LIDX(base + 2 * Q)], d = X[LIDX(base + 3 * Q)];
    float2 t0 = cadd(a, cc), t1 = csub(a, cc), t2 = cadd(b, d), bd = csub(b, d);
    float2 t3 = make_float2(bd.y, -bd.x);
    X[LIDX(base)]         = cadd(t0, t2);
    X[LIDX(base + Q)]     = cmul(cadd(t1, t3), w1);
    X[LIDX(base + 2 * Q)] = cmul(csub(t0, t2), w2);
    X[LIDX(base + 3 * Q)] = cmul(csub(t1, t3), w3);
  }
}

template <int Q, int OFF>
__device__ __forceinline__ void inv_stage_t(float2* __restrict__ X,
    const float2* __restrict__ Tw, int j) {
  const int pos = j & (Q - 1);
  const int base = ((j - pos) << 2) + pos;
  const float2 w1 = Tw[OFF + pos];
  const float2 w2 = Tw[OFF + Q + pos];
  const float2 w3 = Tw[OFF + 2 * Q + pos];
  float2 a = X[LIDX(base)];
  float2 b = cmul(X[LIDX(base + Q)], w1);
  float2 cc = cmul(X[LIDX(base + 2 * Q)], w2);
  float2 d = cmul(X[LIDX(base + 3 * Q)], w3);
  float2 t0 = cadd(a, cc), t1 = csub(a, cc), t2 = cadd(b, d), bd = csub(b, d);
  float2 t3 = make_float2(-bd.y, bd.x);
  X[LIDX(base)]         = cadd(t0, t2);
  X[LIDX(base + Q)]     = cadd(t1, t3);
  X[LIDX(base + 2 * Q)] = csub(t0, t2);
  X[LIDX(base + 3 * Q)] = csub(t1, t3);
}

__device__ __forceinline__ int rev4d(int v) {
  return ((v & 3) << 6) | (((v >> 2) & 3) << 4) | (((v >> 4) & 3) << 2) | ((v >> 6) & 3);
}

// grid (500, 8)
__global__ __launch_bounds__(256) void k_fft(const float* __restrict__ Pb,
    const float* __restrict__ z, const float2* __restrict__ twg,
    const float* __restrict__ wing, float* __restrict__ out) {
  const int u = blockIdx.x, b = blockIdx.y;
  const int tA = 2 * u, tB = tA + 1;
  const int btA = b * T_LEN + tA, btB = btA + 1;
  const int j = threadIdx.x;
  __shared__ float2 WlA[1280];
  __shared__ float2 WlB[1280];
  __shared__ float2 Tws[1020];
  for (int e = j; e < 1020; e += 256) Tws[e] = twg[e];

  const float* zb = z + b * 256000;
  // frame inputs (f1A == f0B shared)
  float f0A = 0.f, fS, f1B = 0.f;
  {
    int zi0 = tA * 256 + j - 255;
    f0A = (zi0 >= 0) ? zb[zi0] : 0.f;
    fS = zb[tA * 256 + j + 1];                       // always in range
    int zi2 = tB * 256 + j + 1;
    f1B = (zi2 < 256000) ? zb[zi2] : 0.f;
  }
  float c1A = 0.f, c2A = 0.f, c1B = 0.f, c2B = 0.f;
  if (j >= 145) {
    int mA = btA * 224 + (j - 145), mB = btB * 224 + (j - 145);
    c1A = (Pb[mA] + Pb[mA + PSTRIDE]) + (Pb[mA + 2 * PSTRIDE] + Pb[mA + 3 * PSTRIDE]);
    c1B = (Pb[mB] + Pb[mB + PSTRIDE]) + (Pb[mB + 2 * PSTRIDE] + Pb[mB + 3 * PSTRIDE]);
  }
  if (j < 111) {
    int mA = btA * 224 + (j + 111), mB = btB * 224 + (j + 111);
    c2A = (Pb[mA] + Pb[mA + PSTRIDE]) + (Pb[mA + 2 * PSTRIDE] + Pb[mA + 3 * PSTRIDE]);
    c2B = (Pb[mB] + Pb[mB + PSTRIDE]) + (Pb[mB + 2 * PSTRIDE] + Pb[mB + 3 * PSTRIDE]);
  }
  __syncthreads();   // Tws ready

  // ---- first fwd stage (M=1024, Q=256, pos=j), sparse inputs, both frames ----
  {
    float2 e1 = Tws[j], e2 = Tws[256 + j], e3 = Tws[512 + j];
    const float2 w1 = make_float2(e1.x, -e1.y);
    const float2 w2 = make_float2(e2.x, -e2.y);
    const float2 w3 = make_float2(e3.x, -e3.y);
    {
      float2 t0 = make_float2(c2A, f0A);
      float2 t1 = make_float2(-c2A, f0A);
      float2 t2 = make_float2(c1A, fS);
      float2 t3 = make_float2(fS, -c1A);
      WlA[LIDX(j)]       = cadd(t0, t2);
      WlA[LIDX(j + 256)] = cmul(cadd(t1, t3), w1);
      WlA[LIDX(j + 512)] = cmul(csub(t0, t2), w2);
      WlA[LIDX(j + 768)] = cmul(csub(t1, t3), w3);
    }
    {
      float2 t0 = make_float2(c2B, fS);
      float2 t1 = make_float2(-c2B, fS);
      float2 t2 = make_float2(c1B, f1B);
      float2 t3 = make_float2(f1B, -c1B);
      WlB[LIDX(j)]       = cadd(t0, t2);
      WlB[LIDX(j + 256)] = cmul(cadd(t1, t3), w1);
      WlB[LIDX(j + 512)] = cmul(csub(t0, t2), w2);
      WlB[LIDX(j + 768)] = cmul(csub(t1, t3), w3);
    }
  }
  __syncthreads();

  fwd_stage2<64, 768>(WlA, WlB, Tws, j);  __syncthreads();   // M=256
  fwd_stage2<16, 960>(WlA, WlB, Tws, j);  __syncthreads();   // M=64
  fwd_stage2<4, 1008>(WlA, WlB, Tws, j);  __syncthreads();   // M=16

  // fwd M=4 (no twiddles) in regs, both frames; publish
  const int base = 4 * j;
  float2 XA[4], XB[4];
  {
    float2 u0 = WlA[LIDX(base)], u1 = WlA[LIDX(base + 1)];
    float2 u2 = WlA[LIDX(base + 2)], u3 = WlA[LIDX(base + 3)];
    float2 t0 = cadd(u0, u2), t1 = csub(u0, u2), t2 = cadd(u1, u3), bd = csub(u1, u3);
    float2 t3 = make_float2(bd.y, -bd.x);
    XA[0] = cadd(t0, t2); XA[1] = cadd(t1, t3); XA[2] = csub(t0, t2); XA[3] = csub(t1, t3);
  }
  {
    float2 u0 = WlB[LIDX(base)], u1 = WlB[LIDX(base + 1)];
    float2 u2 = WlB[LIDX(base + 2)], u3 = WlB[LIDX(base + 3)];
    float2 t0 = cadd(u0, u2), t1 = csub(u0, u2), t2 = cadd(u1, u3), bd = csub(u1, u3);
    float2 t3 = make_float2(bd.y, -bd.x);
    XB[0] = cadd(t0, t2); XB[1] = cadd(t1, t3); XB[2] = csub(t0, t2); XB[3] = csub(t1, t3);
  }
#pragma unroll
  for (int q = 0; q < 4; ++q) { WlA[LIDX(base + q)] = XA[q]; WlB[LIDX(base + q)] = XB[q]; }
  __syncthreads();

  // Hermitian unpack + pointwise per frame, pack Z = S_A + i*S_B (registers)
  const int r0 = rev4d(j);
  const bool self0 = (r0 == 0);
  const int jp = self0 ? 0 : rev4d((256 - r0) & 255);
  float2 PA[4], PB[4];
#pragma unroll
  for (int q = 0; q < 4; ++q) { PA[q] = WlA[LIDX(4 * jp + q)]; PB[q] = WlB[LIDX(4 * jp + q)]; }
  float2 Z[4];
#pragma unroll
  for (int q = 0; q < 4; ++q) {
    float2 SA, SB;
    {
      float2 A = XA[q];
      float2 Bc = self0 ? PA[(4 - q) & 3] : PA[3 - q];
      float2 Y = make_float2(0.5f * (A.x + Bc.x), 0.5f * (A.y - Bc.y));
      float2 F = make_float2(0.5f * (A.y + Bc.y), -0.5f * (A.x - Bc.x));
      float mag = __expf(Y.x * 2.30258509299404568402f);
      float sy, cy;
      __sincosf(Y.y, &sy, &cy);
      float gr = mag * cy, gi = mag * sy;
      SA = make_float2(fmaf(F.x, gr, F.y * gi), fmaf(F.x, gi, -(F.y * gr)));
    }
    {
      float2 A = XB[q];
      float2 Bc = self0 ? PB[(4 - q) & 3] : PB[3 - q];
      float2 Y = make_float2(0.5f * (A.x + Bc.x), 0.5f * (A.y - Bc.y));
      float2 F = make_float2(0.5f * (A.y + Bc.y), -0.5f * (A.x - Bc.x));
      float mag = __expf(Y.x * 2.30258509299404568402f);
      float sy, cy;
      __sincosf(Y.y, &sy, &cy);
      float gr = mag * cy, gi = mag * sy;
      SB = make_float2(fmaf(F.x, gr, F.y * gi), fmaf(F.x, gi, -(F.y * gr)));
    }
    Z[q] = make_float2(SA.x - SB.y, SA.y + SB.x);   // S_A + i*S_B
  }
  __syncthreads();   // all partner reads complete before overwrite

  // inverse M=4 (no twiddles) on Z -> WlA
  {
    float2 t0 = cadd(Z[0], Z[2]), t1 = csub(Z[0], Z[2]), t2 = cadd(Z[1], Z[3]), bd = csub(Z[1], Z[3]);
    float2 t3 = make_float2(-bd.y, bd.x);
    WlA[LIDX(base)]     = cadd(t0, t2);
    WlA[LIDX(base + 1)] = cadd(t1, t3);
    WlA[LIDX(base + 2)] = csub(t0, t2);
    WlA[LIDX(base + 3)] = csub(t1, t3);
  }
  __syncthreads();

  inv_stage_t<4, 1008>(WlA, Tws, j);  __syncthreads();   // M=16
  inv_stage_t<16, 960>(WlA, Tws, j);  __syncthreads();   // M=64
  inv_stage_t<64, 768>(WlA, Tws, j);  __syncthreads();   // M=256

  // ---- final inverse stage (M=1024) inlined, full complex C[j], C[j+256] ----
  {
    float2 w1 = Tws[j], w2 = Tws[256 + j], w3 = Tws[512 + j];
    float2 a = WlA[LIDX(j)];
    float2 bb = cmul(WlA[LIDX(j + 256)], w1);
    float2 cc = cmul(WlA[LIDX(j + 512)], w2);
    float2 d = cmul(WlA[LIDX(j + 768)], w3);
    float2 t0 = cadd(a, cc), t1 = csub(a, cc), t2 = cadd(bb, d), bd = csub(bb, d);
    float2 t3 = make_float2(-bd.y, bd.x);
    float2 Cj    = cadd(t0, t2);   // C[j]     -> corr n1 = 511-j (r-part)
    float2 Cj256 = cadd(t1, t3);   // C[j+256] -> corr n2 = 255-j (l-part)
    int n1 = 511 - j, n2 = 255 - j;
    float wn1 = wing[n1], wn2 = wing[n2];
    // frame A: l -> row tA col n2 ; r -> row tB col n2
    // frame B: l -> row tB col n2 ; r -> row tB+1 (wrap) col n2
    float vA_l = Cj256.x * wn2;
    float vAB  = Cj.x * wn1 + Cj256.y * wn2;   // A.r + B.l, same address
    float vB_r = Cj.y * wn1;
    int tw = (tB + 1 == T_LEN) ? 0 : tB + 1;
    float* ob = out + b * 256000;
    atomicAdd(&ob[tA * 256 + n2], vA_l);
    atomicAdd(&ob[tB * 256 + n2], vAB);
    atomicAdd(&ob[tw * 256 + n2], vB_r);
  }
}

extern "C" void kernel_launch(void* const* d_in, const int* in_sizes, int n_in,
                              void* d_out, int out_size, void* d_ws, size_t ws_size,
                              hipStream_t stream) {
  const float* x  = (const float*)d_in[0];
  const float* z  = (const float*)d_in[1];
  const float* W1 = (const float*)d_in[2];
  const float* b1 = (const float*)d_in[3];
  const float* W2 = (const float*)d_in[4];
  const float* b2 = (const float*)d_in[5];
  const float* W3 = (const float*)d_in[6];
  const float* b3 = (const float*)d_in[7];
  const float* W4 = (const float*)d_in[8];
  const float* b4 = (const float*)d_in[9];

  float* ws   = (float*)d_ws;
  float* bufA = ws;                      // 2,048,000 (h1)
  __hip_bfloat16* h3bf = (__hip_bfloat16*)(ws + 2048000);  // 1,024,000 f32 slots
  float* Pb   = ws + 3072000;            // 4 x 1,792,000 = 7,168,000
  float* Wt1  = ws + 10240000;           //    61,440
  float* Wt2  = ws + 10301440;           //    24,576
  float* Wt3  = ws + 10326016;           //    24,576
  __hip_bfloat16* Wc = (__hip_bfloat16*)(ws + 10350592);   // 98,304 f32 slots
  float2* twTab = (float2*)(ws + 10448896);                // 1020 float2
  float* winTab = ws + 10450944;                           // 512
  float* out = (float*)d_out;

  dim3 blk(256);
  k_prep<<<2206, blk, 0, stream>>>(W1, W2, W3, W4, Wt1, Wt2, Wt3, Wc,
                                   twTab, winTab, out);

  dim3 cgrid10(T_LEN / 10, B_N);   // (100, 8)
  k_conv1t<<<cgrid10, blk, 0, stream>>>(x, Wt1, b1, bufA);
  k_convg2<<<cgrid10, blk, 0, stream>>>(bufA, Wt2, b2, Wt3, b3, h3bf);
  dim3 g4(16, B_N, 4);
  k_conv4m<<<g4, blk, 0, stream>>>(h3bf, Wc, b4, Pb);
  dim3 gf(T_LEN / 2, B_N);         // (500, 8)
  k_fft<<<gf, blk, 0, stream>>>(Pb, z, twTab, winTab, out);
}